// Round 4
// baseline (342.650 us; speedup 1.0000x reference)
//
#include <hip/hip_runtime.h>
#include <math.h>

// Problem constants: B=2, L=4096, d_model=1024, H=16, M=D=64
#define BATCH 2
#define SEQ   4096
#define DM    1024
#define NH    16
#define MD    64
#define NROW  (BATCH*SEQ)     // 8192
#define RQ    (BATCH*SEQ*NH)  // 131072
#define NCHUNK 64
#define CT     64
#define DN    0.35355339059327373f
#define INV_SQRT_M 0.125f
#define PITCH 72              // ushort row pitch for bf16 LDS tiles
#define STSZ  (65*64)         // per-(bh,c) S^T chunk: rows d=0..64 (row 64 = z)
#define DIAG_SCALE (0.125f * 0.0625f)   // DN^2 * 0.5*DN^2

typedef unsigned short ushort_t;
typedef short bf8_t __attribute__((ext_vector_type(8)));
typedef float f4_t  __attribute__((ext_vector_type(4)));
typedef ushort_t us8_t __attribute__((ext_vector_type(8)));

__device__ static inline ushort_t f2bf(float f) {
    union { float f; unsigned u; } v; v.f = f;
    unsigned r = v.u + 0x7FFFu + ((v.u >> 16) & 1u);   // RNE
    return (ushort_t)(r >> 16);
}
__device__ static inline float bf2f(ushort_t u) {
    union { unsigned u; float f; } v; v.u = ((unsigned)u) << 16;
    return v.f;
}

__device__ static inline void async_ld16(const ushort_t* g, ushort_t* l) {
    __builtin_amdgcn_global_load_lds(
        (const __attribute__((address_space(1))) unsigned int*)g,
        (__attribute__((address_space(3))) unsigned int*)l,
        16, 0, 0);
}

__device__ static inline void sbar() {
    __builtin_amdgcn_sched_barrier(0);
    __builtin_amdgcn_s_barrier();
    __builtin_amdgcn_sched_barrier(0);
}
#define VMCNT(n) do { asm volatile("s_waitcnt vmcnt(" #n ")" ::: "memory"); \
                      __builtin_amdgcn_sched_barrier(0); } while (0)

// ---------------------------------------------------------------------------
// 256x256-tile GEMM core (m201 geometry): 512 threads = 8 waves (2M x 4N),
// per-wave output 128x64 (acc[8][4] -> 0.375 LDS reads/MFMA), BK=64, K=1024.
// LDS: A[2][256][64] + B[2][256][64] bf16 = 128 KiB -> 1 block/CU.
//
// 4 phases per K-tile u (buf s=u&1), each phase:
//   {4-8 ds_read_b128 | stage ONE 16KB half (2 global_load_lds) | vmcnt(4) |
//    bar | setprio1 16 MFMA setprio0 | bar}
// Phase p reads (ks,ih) = (p>>1, p&1): ph0 A-h0+B(ks0), ph1 A-h1(ks0, B kept
// in regs), ph2 A-h0+B(ks1), ph3 A-h1(ks1).
// Stage schedule per tile u: ph0 Bh1(u+1), ph1 Ah0(u+1), ph2 Ah1(u+1),
// ph3 Bh0(u+2).  Ledger (2 loads/phase, per-wave): at each VMCNT(4), the
// queue is [X, Y, Z] (6) and the wait publishes X = exactly the half needed
// by the NEXT phase; every staged region is >=1 barrier past its last
// reader (A-h0/B free after ph2-bar, A-h1 after ph3-bar). Drain to 0 only
// at the final tile (tail waits 4/4/4/2/0).
// T2 swizzle: LDS dest linear; global SOURCE col pre-XOR'd
// (kcol=((l&7)^(l>>3))*8); read slot XOR'd with row&7. Conflict-free b128
// (HW-verified: SQ_LDS_BANK_CONFLICT = 0).
// ---------------------------------------------------------------------------
#define BUFE (256*64)   // ushorts per buffer per matrix (32 KiB)

__device__ static inline void gemm256_core(
    const ushort_t* __restrict__ A, const ushort_t* __restrict__ BT,
    ushort_t* As, ushort_t* Bs, int bm, int bn, int tid, f4_t acc[8][4])
{
    const int lane = tid & 63, w = tid >> 6;        // 8 waves
    const int wr = w >> 2, wc = w & 3;              // 2 x 4 wave grid
    const int quad = lane >> 4, l15 = lane & 15;
    const int lrow = lane >> 3;                     // 0..7
    const int kcol = ((lane & 7) ^ lrow) * 8;       // inverse-swizzled src col

    // stage half h (128 rows) of tile t into buffer s: 2 loads/thread.
    auto stA = [&](int t, int s, int h) {
        #pragma unroll
        for (int c = 0; c < 2; ++c) {
            const int r0 = h * 128 + c * 64 + w * 8;
            async_ld16(A + (size_t)(bm + r0 + lrow) * DM + t * 64 + kcol,
                       &As[s * BUFE + r0 * 64]);
        }
    };
    auto stB = [&](int t, int s, int h) {
        #pragma unroll
        for (int c = 0; c < 2; ++c) {
            const int r0 = h * 128 + c * 64 + w * 8;
            async_ld16(BT + (size_t)(bn + r0 + lrow) * DM + t * 64 + kcol,
                       &Bs[s * BUFE + r0 * 64]);
        }
    };

    bf8_t af[4], bf[4];
    auto rdB = [&](int s, int ks) {
        const int slot8 = (((ks << 2) | quad) ^ (l15 & 7)) * 8;
        #pragma unroll
        for (int j = 0; j < 4; ++j)
            bf[j] = *(const bf8_t*)&Bs[s * BUFE + (wc * 64 + j * 16 + l15) * 64 + slot8];
    };
    auto rdA = [&](int s, int ks, int ih) {
        const int slot8 = (((ks << 2) | quad) ^ (l15 & 7)) * 8;
        #pragma unroll
        for (int i = 0; i < 4; ++i)
            af[i] = *(const bf8_t*)&As[s * BUFE + (wr * 128 + (ih * 4 + i) * 16 + l15) * 64 + slot8];
    };
    auto mm = [&](int ih) {
        __builtin_amdgcn_s_setprio(1);
        #pragma unroll
        for (int i = 0; i < 4; ++i)
            #pragma unroll
            for (int j = 0; j < 4; ++j)
                acc[ih * 4 + i][j] = __builtin_amdgcn_mfma_f32_16x16x32_bf16(
                    af[i], bf[j], acc[ih * 4 + i][j], 0, 0, 0);
        __builtin_amdgcn_s_setprio(0);
    };

    // prologue: tile0 (4 halves) + Bh0(1) = 10 loads; vmcnt(4) publishes
    // Bh0(0),Bh1(0),Ah0(0), leaving [Ah1(0), Bh0(1)] = 4 in flight.
    stB(0, 0, 0); stB(0, 0, 1); stA(0, 0, 0); stA(0, 0, 1); stB(1, 1, 0);
    VMCNT(4); sbar();

    #pragma unroll 1
    for (int v = 0; v < 7; ++v) {
        const int u = 2 * v;                        // tiles u (buf0), u+1 (buf1)
        rdA(0,0,0); rdB(0,0); stB(u+1, 1, 1); VMCNT(4); sbar(); mm(0); sbar();
        rdA(0,0,1);           stA(u+1, 1, 0); VMCNT(4); sbar(); mm(1); sbar();
        rdA(0,1,0); rdB(0,1); stA(u+1, 1, 1); VMCNT(4); sbar(); mm(0); sbar();
        rdA(0,1,1);           stB(u+2, 0, 0); VMCNT(4); sbar(); mm(1); sbar();

        rdA(1,0,0); rdB(1,0); stB(u+2, 0, 1); VMCNT(4); sbar(); mm(0); sbar();
        rdA(1,0,1);           stA(u+2, 0, 0); VMCNT(4); sbar(); mm(1); sbar();
        rdA(1,1,0); rdB(1,1); stA(u+2, 0, 1); VMCNT(4); sbar(); mm(0); sbar();
        rdA(1,1,1);           stB(u+3, 1, 0); VMCNT(4); sbar(); mm(1); sbar();
    }
    // tile 14 (buf 0): stages complete tile 15; waits tighten 4/4/4/2.
    rdA(0,0,0); rdB(0,0); stB(15, 1, 1); VMCNT(4); sbar(); mm(0); sbar();
    rdA(0,0,1);           stA(15, 1, 0); VMCNT(4); sbar(); mm(1); sbar();
    rdA(0,1,0); rdB(0,1); stA(15, 1, 1); VMCNT(4); sbar(); mm(0); sbar();
    rdA(0,1,1);                           VMCNT(2); sbar(); mm(1); sbar();
    VMCNT(0); sbar();                     // tile 15 fully resident
    // tile 15 (buf 1): no stages, no waits needed.
    rdA(1,0,0); rdB(1,0); mm(0);
    rdA(1,0,1);           mm(1);
    rdA(1,1,0); rdB(1,1); mm(0);
    rdA(1,1,1);           mm(1);
}

// ---------------------------------------------------------------------------
// prep: 4x transpose_cvt (z selects weight) + zero kmOrd.
// ---------------------------------------------------------------------------
__global__ __launch_bounds__(256) void prep_weights(
    const float* __restrict__ W0, const float* __restrict__ W1,
    const float* __restrict__ W2, const float* __restrict__ W3,
    ushort_t* __restrict__ WT, unsigned* __restrict__ kmOrd)
{
    if (blockIdx.z == 0 && blockIdx.x == 0 && blockIdx.y == 0 && threadIdx.x < 32)
        kmOrd[threadIdx.x] = 0u;
    const float* W = blockIdx.z == 0 ? W0 : (blockIdx.z == 1 ? W1 : (blockIdx.z == 2 ? W2 : W3));
    ushort_t* dst = WT + (size_t)blockIdx.z * DM * DM;
    __shared__ float t[32][33];
    const int k0 = blockIdx.x * 32, n0 = blockIdx.y * 32;
    const int tx = threadIdx.x & 31, ty = threadIdx.x >> 5;
    #pragma unroll
    for (int r = 0; r < 32; r += 8)
        t[ty + r][tx] = W[(size_t)(k0 + ty + r) * 1024 + n0 + tx];
    __syncthreads();
    #pragma unroll
    for (int r = 0; r < 32; r += 8)
        dst[(size_t)(n0 + ty + r) * 1024 + k0 + tx] = f2bf(t[tx][ty + r]);
}

// ---------------------------------------------------------------------------
// fused fp32 -> bf16 convert for q,k,v
// ---------------------------------------------------------------------------
__global__ __launch_bounds__(256) void cvt_qkv(
    const float* __restrict__ Q, const float* __restrict__ K,
    const float* __restrict__ V, ushort_t* __restrict__ Y)
{
    const int y = blockIdx.y;
    const float* X = y == 0 ? Q : (y == 1 ? K : V);
    ushort_t* dst = Y + (size_t)y * NROW * DM;
    int i = blockIdx.x * 256 + threadIdx.x;
    const float4* X4 = (const float4*)X;
    float4 a = X4[i * 2], b = X4[i * 2 + 1];
    us8_t o;
    o[0]=f2bf(a.x); o[1]=f2bf(a.y); o[2]=f2bf(a.z); o[3]=f2bf(a.w);
    o[4]=f2bf(b.x); o[5]=f2bf(b.y); o[6]=f2bf(b.z); o[7]=f2bf(b.w);
    *(us8_t*)&dst[i * 8] = o;
}

// ---------------------------------------------------------------------------
// merged QKV GEMM (256^2 tiles): 384 blocks = 3z x 32bm x 4bn.
// XCD-chunked swizzle: xcd = bx&7 gets bm panels [xcd*4, xcd*4+4) for all
// z and bn (bn fastest) -> B L2-resident, A panel reused 4x per XCD.
// z==1 (keys) folds per-(b,h) output max into kmOrd via ordered-uint atomicMax.
// ---------------------------------------------------------------------------
__global__ __launch_bounds__(512, 2) void gemm_qkv(
    const ushort_t* __restrict__ Xc, const ushort_t* __restrict__ WT,
    const float* __restrict__ bq, const float* __restrict__ bk,
    const float* __restrict__ bv, ushort_t* __restrict__ Obase,
    unsigned* __restrict__ kmOrd)
{
    __shared__ ushort_t As[2 * BUFE];
    __shared__ ushort_t Bs[2 * BUFE];
    const int bx = blockIdx.x;
    const int xcd = bx & 7, idx = bx >> 3;          // idx 0..47
    const int z = idx >> 4;                         // 0..2
    const int rem = idx & 15;
    const int bm = ((xcd << 2) + (rem >> 2)) << 8;  // 32 bm panels
    const int bn = (rem & 3) << 8;                  // 4 bn panels

    const ushort_t* A  = Xc + (size_t)z * NROW * DM;
    const ushort_t* BT = WT + (size_t)z * DM * DM;
    const float* bias = z == 0 ? bq : (z == 1 ? bk : bv);
    ushort_t* Cbf = Obase + (size_t)z * NROW * DM;

    const int tid = threadIdx.x;
    const int lane = tid & 63, w = tid >> 6;
    const int wr = w >> 2, wc = w & 3;
    const int quad = lane >> 4, l15 = lane & 15;

    f4_t acc[8][4] = {};
    gemm256_core(A, BT, As, Bs, bm, bn, tid, acc);

    float mx = -3.4e38f;
    #pragma unroll
    for (int j = 0; j < 4; ++j) {
        const int col = bn + wc * 64 + j * 16 + l15;
        const float bb = bias[col];
        #pragma unroll
        for (int i = 0; i < 8; ++i) {
            const int row0 = bm + wr * 128 + i * 16 + quad * 4;
            #pragma unroll
            for (int r = 0; r < 4; ++r) {
                float v = acc[i][j][r] + bb;
                mx = fmaxf(mx, v);
                Cbf[(size_t)(row0 + r) * DM + col] = f2bf(v);
            }
        }
    }
    if (z == 1) {
        // wave covers one (b,h): rows bm..bm+255 (one b), cols bn+wc*64..+64.
        #pragma unroll
        for (int off = 32; off; off >>= 1) mx = fmaxf(mx, __shfl_xor(mx, off));
        if (lane == 0) {
            const int b = bm >> 12;
            const int h = (bn + wc * 64) >> 6;
            unsigned ub = __float_as_uint(mx);
            unsigned enc = (ub & 0x80000000u) ? ~ub : (ub | 0x80000000u);
            atomicMax(&kmOrd[b * NH + h], enc);
        }
    }
}

// ---------------------------------------------------------------------------
// final GEMM (256^2 tiles, 128 blocks): obf @ WoT + bo -> fp32 d_out
// ---------------------------------------------------------------------------
__global__ __launch_bounds__(512, 2) void gemm_out(
    const ushort_t* __restrict__ A, const ushort_t* __restrict__ BT,
    const float* __restrict__ bias, float* __restrict__ C)
{
    __shared__ ushort_t As[2 * BUFE];
    __shared__ ushort_t Bs[2 * BUFE];
    const int bx = blockIdx.x;
    const int xcd = bx & 7, idx = bx >> 3;          // idx 0..15
    const int bm = ((xcd << 2) + (idx >> 2)) << 8;
    const int bn = (idx & 3) << 8;

    const int tid = threadIdx.x;
    const int lane = tid & 63, w = tid >> 6;
    const int wr = w >> 2, wc = w & 3;
    const int quad = lane >> 4, l15 = lane & 15;

    f4_t acc[8][4] = {};
    gemm256_core(A, BT, As, Bs, bm, bn, tid, acc);

    #pragma unroll
    for (int j = 0; j < 4; ++j) {
        const int col = bn + wc * 64 + j * 16 + l15;
        const float bb = bias[col];
        #pragma unroll
        for (int i = 0; i < 8; ++i) {
            const int row0 = bm + wr * 128 + i * 16 + quad * 4;
            #pragma unroll
            for (int r = 0; r < 4; ++r)
                C[(size_t)(row0 + r) * DM + col] = acc[i][j][r] + bb;
        }
    }
}

// ---------------------------------------------------------------------------
// FAVOR feature map for K (MFMA), in-place on bf16 X [RQ,64].
// ---------------------------------------------------------------------------
__global__ __launch_bounds__(256) void favor_k_mfma(
    ushort_t* __restrict__ X, const float* __restrict__ Wf,
    const unsigned* __restrict__ kmOrd)
{
    __shared__ ushort_t Xs[64 * PITCH];
    __shared__ ushort_t Ws[64 * PITCH];
    __shared__ float ssp[64][4];
    __shared__ float diag[64], mxr[64];
    const int tid = threadIdx.x;
    const int lane = tid & 63, w = tid >> 6;
    const int quad = lane >> 4, l15 = lane & 15;
    const int rbase = blockIdx.x * 64;

    #pragma unroll
    for (int r = 0; r < 2; ++r) {
        int idx = tid + r * 256;
        int row = idx >> 3, ch = idx & 7;
        *(us8_t*)&Xs[row * PITCH + ch * 8] =
            *(const us8_t*)&X[(size_t)(rbase + row) * 64 + ch * 8];
    }
    const float4* Wf4 = (const float4*)Wf;
    #pragma unroll
    for (int i = 0; i < 4; ++i) {
        int f4i = tid + i * 256;
        int row = f4i >> 4, q4 = f4i & 15;
        float4 wv = Wf4[f4i];
        Ws[row * PITCH + q4 * 4 + 0] = f2bf(DN * wv.x);
        Ws[row * PITCH + q4 * 4 + 1] = f2bf(DN * wv.y);
        Ws[row * PITCH + q4 * 4 + 2] = f2bf(DN * wv.z);
        Ws[row * PITCH + q4 * 4 + 3] = f2bf(DN * wv.w);
    }
    __syncthreads();

    {
        const int row = tid >> 2, seg = tid & 3;
        const us8_t* xp = (const us8_t*)&Xs[row * PITCH + seg * 16];
        us8_t a = xp[0], b2 = xp[1];
        float ss = 0.f;
        #pragma unroll
        for (int j = 0; j < 8; ++j) {
            float x0 = bf2f(a[j]), x1 = bf2f(b2[j]);
            ss += x0 * x0 + x1 * x1;
        }
        ssp[row][seg] = ss;
    }
    __syncthreads();
    if (tid < 64) {
        diag[tid] = (ssp[tid][0] + ssp[tid][1] + ssp[tid][2] + ssp[tid][3]) * DIAG_SCALE;
        int rg = rbase + tid;
        int h = rg & (NH - 1);
        int b = rg >> 16;
        unsigned u = kmOrd[b * NH + h];
        unsigned bits = (u & 0x80000000u) ? (u & 0x7FFFFFFFu) : ~u;
        mxr[tid] = DN * __uint_as_float(bits);
    }
    __syncthreads();

    bf8_t xf[2];
    #pragma unroll
    for (int ks = 0; ks < 2; ++ks)
        xf[ks] = *(const bf8_t*)&Xs[(w * 16 + l15) * PITCH + ks * 32 + quad * 8];
    f4_t acc[4] = {};
    #pragma unroll
    for (int dt = 0; dt < 4; ++dt)
        #pragma unroll
        for (int ks = 0; ks < 2; ++ks) {
            bf8_t wfr = *(const bf8_t*)&Ws[(dt * 16 + l15) * PITCH + ks * 32 + quad * 8];
            acc[dt] = __builtin_amdgcn_mfma_f32_16x16x32_bf16(xf[ks], wfr, acc[dt], 0, 0, 0);
        }
    __syncthreads();

    #pragma unroll
    for (int r = 0; r < 4; ++r) {
        int row = w * 16 + quad * 4 + r;
        float d_ = diag[row], m_ = mxr[row];
        #pragma unroll
        for (int dt = 0; dt < 4; ++dt) {
            float e = acc[dt][r] - d_ - m_ + 1e-8f;
            X[(size_t)(rbase + row) * 64 + dt * 16 + l15] = f2bf(INV_SQRT_M * expf(e));
        }
    }
}

// ---------------------------------------------------------------------------
// chunk_sums (MFMA): S^T[d][m] = sum_t V[t][d]*K[t][m]; row 64 = z[m]. bf16 out.
// ---------------------------------------------------------------------------
__global__ __launch_bounds__(256) void chunk_sums_mfma(
    const ushort_t* __restrict__ Kbf, const ushort_t* __restrict__ Vbf,
    ushort_t* __restrict__ ST)
{
    const int bx = blockIdx.x;
    const int c = bx & 63, h = (bx >> 6) & 15, b = bx >> 10;
    __shared__ ushort_t Kt[64 * PITCH];
    __shared__ ushort_t Vt[80 * PITCH];
    const int tid = threadIdx.x;
    const int lane = tid & 63, w = tid >> 6;
    const int quad = lane >> 4, l15 = lane & 15;

    const size_t gbase = ((size_t)(b * SEQ + c * CT)) * DM + h * MD;
    #pragma unroll
    for (int r = 0; r < 2; ++r) {
        int ch = w + r * 4;
        int t = lane;
        us8_t kv = *(const us8_t*)&Kbf[gbase + (size_t)t * DM + ch * 8];
        us8_t vv = *(const us8_t*)&Vbf[gbase + (size_t)t * DM + ch * 8];
        #pragma unroll
        for (int j = 0; j < 8; ++j) {
            Kt[(ch * 8 + j) * PITCH + t] = kv[j];
            Vt[(ch * 8 + j) * PITCH + t] = vv[j];
        }
    }
    if (tid < 64) Vt[64 * PITCH + tid] = (ushort_t)0x3F80;
    __syncthreads();

    ushort_t* Sg = ST + (size_t)((b * NH + h) * NCHUNK + c) * STSZ;

    bf8_t vf[2];
    #pragma unroll
    for (int ks = 0; ks < 2; ++ks)
        vf[ks] = *(const bf8_t*)&Vt[(w * 16 + l15) * PITCH + ks * 32 + quad * 8];
    f4_t acc[4] = {};
    #pragma unroll
    for (int mt = 0; mt < 4; ++mt)
        #pragma unroll
        for (int ks = 0; ks < 2; ++ks) {
            bf8_t kf = *(const bf8_t*)&Kt[(mt * 16 + l15) * PITCH + ks * 32 + quad * 8];
            acc[mt] = __builtin_amdgcn_mfma_f32_16x16x32_bf16(vf[ks], kf, acc[mt], 0, 0, 0);
        }
    #pragma unroll
    for (int mt = 0; mt < 4; ++mt)
        #pragma unroll
        for (int r = 0; r < 4; ++r)
            Sg[(w * 16 + quad * 4 + r) * 64 + mt * 16 + l15] = f2bf(acc[mt][r]);

    if (w == 0) {
        bf8_t vf4[2];
        #pragma unroll
        for (int ks = 0; ks < 2; ++ks)
            vf4[ks] = *(const bf8_t*)&Vt[(64 + l15) * PITCH + ks * 32 + quad * 8];
        f4_t accz[4] = {};
        #pragma unroll
        for (int mt = 0; mt < 4; ++mt)
            #pragma unroll
            for (int ks = 0; ks < 2; ++ks) {
                bf8_t kf = *(const bf8_t*)&Kt[(mt * 16 + l15) * PITCH + ks * 32 + quad * 8];
                accz[mt] = __builtin_amdgcn_mfma_f32_16x16x32_bf16(vf4[ks], kf, accz[mt], 0, 0, 0);
            }
        if (quad == 0) {
            #pragma unroll
            for (int mt = 0; mt < 4; ++mt)
                Sg[64 * 64 + mt * 16 + l15] = f2bf(accz[mt][0]);
        }
    }
}

// ---------------------------------------------------------------------------
// Exclusive prefix over chunks on bf16 ST; register-pipelined (all 64 loads
// issued before the scan — kills the 64-deep serial latency chain).
// ---------------------------------------------------------------------------
__global__ __launch_bounds__(256) void prefix_scan_st(ushort_t* __restrict__ ST)
{
    const int sb = blockIdx.x / 17;
    const int e = (blockIdx.x % 17) * 256 + threadIdx.x;
    if (e >= STSZ) return;
    ushort_t* p = ST + (size_t)sb * NCHUNK * STSZ + e;
    ushort_t v[NCHUNK];
    #pragma unroll
    for (int c = 0; c < NCHUNK; ++c) v[c] = p[(size_t)c * STSZ];
    float run = 0.f;
    #pragma unroll
    for (int c = 0; c < NCHUNK; ++c) {
        float cur = bf2f(v[c]);
        p[(size_t)c * STSZ] = f2bf(run);
        run += cur;
    }
}

// ---------------------------------------------------------------------------
// intra-chunk causal attention (MFMA) with inline FAVOR-q.
// ---------------------------------------------------------------------------
__global__ __launch_bounds__(256) void intra_attn_mfma(
    const ushort_t* __restrict__ Qraw, const ushort_t* __restrict__ Kbf,
    const ushort_t* __restrict__ Vbf, const ushort_t* __restrict__ ST,
    const float* __restrict__ Wfq, ushort_t* __restrict__ Obf)
{
    const int bx = blockIdx.x;
    const int c = bx & 63, h = (bx >> 6) & 15, b = bx >> 10;
    __shared__ ushort_t Qs[64 * PITCH];
    __shared__ ushort_t Ks[64 * PITCH];
    __shared__ ushort_t Vt[80 * PITCH];
    __shared__ ushort_t St[80 * PITCH];
    __shared__ ushort_t Ws[64 * PITCH];
    __shared__ float ssp[64][4];
    __shared__ float mxp[64][4];
    __shared__ float diag[64], mxr[64], dens[64];
    const int tid = threadIdx.x;
    const int lane = tid & 63, w = tid >> 6;
    const int quad = lane >> 4, l15 = lane & 15;

    const size_t gbase = ((size_t)(b * SEQ + c * CT)) * DM + h * MD;

    #pragma unroll
    for (int r = 0; r < 2; ++r) {
        int idx = tid + r * 256;
        int row = idx >> 3, ch = idx & 7;
        us8_t qv = *(const us8_t*)&Qraw[gbase + (size_t)row * DM + ch * 8];
        us8_t kv = *(const us8_t*)&Kbf[gbase + (size_t)row * DM + ch * 8];
        *(us8_t*)&Qs[row * PITCH + ch * 8] = qv;
        *(us8_t*)&Ks[row * PITCH + ch * 8] = kv;
    }
    #pragma unroll
    for (int r = 0; r < 2; ++r) {
        int ch = w + r * 4;
        int t = lane;
        us8_t vv = *(const us8_t*)&Vbf[gbase + (size_t)t * DM + ch * 8];
        #pragma unroll
        for (int j = 0; j < 8; ++j) Vt[(ch * 8 + j) * PITCH + t] = vv[j];
    }
    #pragma unroll
    for (int r = 0; r < 4; ++r) {
        int idx = tid + r * 256;
        int row = 64 + (idx >> 6), t = idx & 63;
        Vt[row * PITCH + t] = (row == 64) ? (ushort_t)0x3F80 : (ushort_t)0;
    }
    const us8_t* Sg8 = (const us8_t*)(ST + (size_t)((b * NH + h) * NCHUNK + c) * STSZ);
    #pragma unroll
    for (int r = 0; r < 3; ++r) {
        int idx = tid + r * 256;
        if (idx < 520) {
            int d = idx >> 3, mo = (idx & 7) * 8;
            *(us8_t*)&St[d * PITCH + mo] = Sg8[idx];
        }
        int idx2 = idx - 520;
        if (idx2 >= 0 && idx2 < 120) {
            int row = 65 + (idx2 >> 3), mo = (idx2 & 7) * 8;
            us8_t z = {};
            *(us8_t*)&St[row * PITCH + mo] = z;
        }
    }
    const float4* Wf4 = (const float4*)Wfq;
    #pragma unroll
    for (int i = 0; i < 4; ++i) {
        int f4i = tid + i * 256;
        int row = f4i >> 4, q4 = f4i & 15;
        float4 wv = Wf4[f4i];
        Ws[row * PITCH + q4 * 4 + 0] = f2bf(DN * wv.x);
        Ws[row * PITCH + q4 * 4 + 1] = f2bf(DN * wv.y);
        Ws[row * PITCH + q4 * 4 + 2] = f2bf(DN * wv.z);
        Ws[row * PITCH + q4 * 4 + 3] = f2bf(DN * wv.w);
    }
    __syncthreads();

    {
        const int row = tid >> 2, seg = tid & 3;
        const us8_t* xp = (const us8_t*)&Qs[row * PITCH + seg * 16];
        us8_t a = xp[0], b2 = xp[1];
        float ss = 0.f, mx = -3.4e38f;
        #pragma unroll
        for (int j = 0; j < 8; ++j) {
            float x0 = bf2f(a[j]), x1 = bf2f(b2[j]);
            ss += x0 * x0 + x1 * x1;
            mx = fmaxf(mx, fmaxf(x0, x1));
        }
        ssp[row][seg] = ss;
        mxp[row][seg] = mx;
    }
    __syncthreads();
    if (tid < 64) {
        diag[tid] = (ssp[tid][0] + ssp[tid][1] + ssp[tid][2] + ssp[tid][3]) * DIAG_SCALE;
        mxr[tid] = DN * fmaxf(fmaxf(mxp[tid][0], mxp[tid][1]),
                              fmaxf(mxp[tid][2], mxp[tid][3]));
    }
    __syncthreads();

    {
        bf8_t xf[2];
        #pragma unroll
        for (int ks = 0; ks < 2; ++ks)
            xf[ks] = *(const bf8_t*)&Qs[(w * 16 + l15) * PITCH + ks * 32 + quad * 8];
        f4_t facc[4] = {};
        #pragma unroll
        for (int dt = 0; dt < 4; ++dt)
            #pragma unroll
            for (int ks = 0; ks < 2; ++ks) {
                bf8_t wfr = *(const bf8_t*)&Ws[(dt * 16 + l15) * PITCH + ks * 32 + quad * 8];
                facc[dt] = __builtin_amdgcn_mfma_f32_16x16x32_bf16(xf[ks], wfr, facc[dt], 0, 0, 0);
            }
        __syncthreads();
        #pragma unroll
        for (int r = 0; r < 4; ++r) {
            int row = w * 16 + quad * 4 + r;
            float d_ = diag[row], m_ = mxr[row];
            #pragma unroll
            for (int dt = 0; dt < 4; ++dt) {
                float e = facc[dt][r] - d_ - m_ + 1e-8f;
                Qs[row * PITCH + dt * 16 + l15] = f2bf(INV_SQRT_M * expf(e));
            }
        }
    }
    __syncthreads();

    bf8_t qf[2];
    #pragma unroll
    for (int ks = 0; ks < 2; ++ks)
        qf[ks] = *(const bf8_t*)&Qs[(w * 16 + l15) * PITCH + ks * 32 + quad * 8];
    f4_t accA[4] = {};
    #pragma unroll
    for (int jt = 0; jt < 4; ++jt)
        #pragma unroll
        for (int ks = 0; ks < 2; ++ks) {
            bf8_t kf = *(const bf8_t*)&Ks[(jt * 16 + l15) * PITCH + ks * 32 + quad * 8];
            accA[jt] = __builtin_amdgcn_mfma_f32_16x16x32_bf16(qf[ks], kf, accA[jt], 0, 0, 0);
        }
    __syncthreads();
    #pragma unroll
    for (int jt = 0; jt < 4; ++jt) {
        int j = jt * 16 + l15;
        #pragma unroll
        for (int r = 0; r < 4; ++r) {
            int i = w * 16 + quad * 4 + r;
            float a = (j <= i) ? accA[jt][r] : 0.f;
            Ks[i * PITCH + j] = f2bf(a);
        }
    }
    __syncthreads();

    bf8_t af[2];
    #pragma unroll
    for (int ks = 0; ks < 2; ++ks)
        af[ks] = *(const bf8_t*)&Ks[(w * 16 + l15) * PITCH + ks * 32 + quad * 8];
    f4_t acc[5] = {};
    #pragma unroll
    for (int dt = 0; dt < 5; ++dt)
        #pragma unroll
        for (int ks = 0; ks < 2; ++ks) {
            bf8_t sf = *(const bf8_t*)&St[(dt * 16 + l15) * PITCH + ks * 32 + quad * 8];
            acc[dt] = __builtin_amdgcn_mfma_f32_16x16x32_bf16(qf[ks], sf, acc[dt], 0, 0, 0);
            bf8_t vf = *(const bf8_t*)&Vt[(dt * 16 + l15) * PITCH + ks * 32 + quad * 8];
            acc[dt] = __builtin_amdgcn_mfma_f32_16x16x32_bf16(af[ks], vf, acc[dt], 0, 0, 0);
        }
    if (l15 == 0) {
        #pragma unroll
        for (int r = 0; r < 4; ++r) dens[w * 16 + quad * 4 + r] = acc[4][r];
    }
    __syncthreads();

    #pragma unroll
    for (int r = 0; r < 4; ++r) {
        int i = w * 16 + quad * 4 + r;
        float inv = 1.0f / dens[i];
        #pragma unroll
        for (int dt = 0; dt < 4; ++dt)
            Obf[gbase + (size_t)i * DM + dt * 16 + l15] = f2bf(acc[dt][r] * inv);
    }
}

// ---------------------------------------------------------------------------
extern "C" void kernel_launch(void* const* d_in, const int* in_sizes, int n_in,
                              void* d_out, int out_size, void* d_ws, size_t ws_size,
                              hipStream_t stream)
{
    const float* queries = (const float*)d_in[0];
    const float* keys    = (const float*)d_in[1];
    const float* values  = (const float*)d_in[2];
    const float* Wq = (const float*)d_in[3];  const float* bq = (const float*)d_in[4];
    const float* Wk = (const float*)d_in[5];  const float* bk = (const float*)d_in[6];
    const float* Wv = (const float*)d_in[7];  const float* bv = (const float*)d_in[8];
    const float* Wo = (const float*)d_in[9];  const float* bo = (const float*)d_in[10];
    const float* Wfq = (const float*)d_in[11];
    const float* Wfk = (const float*)d_in[12];

    char* ws = (char*)d_ws;
    unsigned* kmOrd = (unsigned*)ws;                       // [32] (pad)
    ushort_t* STb = (ushort_t*)(ws + 256);                 // [32,64,65*64] bf16
    ushort_t* qbf = STb + (size_t)32 * NCHUNK * STSZ;      // qkv bf16 GEMM outputs (contiguous)
    ushort_t* kbf = qbf + (size_t)NROW * DM;
    ushort_t* vbf = kbf + (size_t)NROW * DM;
    ushort_t* obf = vbf + (size_t)NROW * DM;               // bf16 attn out
    ushort_t* xcvt = obf + (size_t)NROW * DM;              // 3x bf16 converted inputs
    ushort_t* wT  = xcvt + (size_t)3 * NROW * DM;          // 4 x [1024,1024] bf16
    ushort_t* WoT = wT + (size_t)3 * DM * DM;

    prep_weights<<<dim3(32, 32, 4), 256, 0, stream>>>(Wq, Wk, Wv, Wo, wT, kmOrd);

    const int n8 = NROW * DM / 8;
    cvt_qkv<<<dim3(n8 / 256, 3), 256, 0, stream>>>(queries, keys, values, xcvt);

    gemm_qkv<<<384, 512, 0, stream>>>(xcvt, wT, bq, bk, bv, qbf, kmOrd);

    favor_k_mfma<<<RQ / 64, 256, 0, stream>>>(kbf, Wfk, kmOrd);

    chunk_sums_mfma<<<BATCH * NH * NCHUNK, 256, 0, stream>>>(kbf, vbf, STb);
    prefix_scan_st<<<32 * 17, 256, 0, stream>>>(STb);
    intra_attn_mfma<<<BATCH * NH * NCHUNK, 256, 0, stream>>>(qbf, kbf, vbf, STb, Wfq, obf);

    gemm_out<<<128, 512, 0, stream>>>(obf, WoT, bo, (float*)d_out);
}

// Round 6
// 328.239 us; speedup vs baseline: 1.0439x; 1.0439x over previous
//
#include <hip/hip_runtime.h>
#include <math.h>

// Problem constants: B=2, L=4096, d_model=1024, H=16, M=D=64
#define BATCH 2
#define SEQ   4096
#define DM    1024
#define NH    16
#define MD    64
#define NROW  (BATCH*SEQ)     // 8192
#define RQ    (BATCH*SEQ*NH)  // 131072
#define NCHUNK 64
#define CT     64
#define DN    0.35355339059327373f
#define INV_SQRT_M 0.125f
#define PITCH 72              // ushort row pitch for bf16 LDS tiles
#define STSZ  (65*64)         // per-(bh,c) S^T chunk: rows d=0..64 (row 64 = z)
#define DIAG_SCALE (0.125f * 0.0625f)   // DN^2 * 0.5*DN^2

typedef unsigned short ushort_t;
typedef short bf8_t __attribute__((ext_vector_type(8)));
typedef float f4_t  __attribute__((ext_vector_type(4)));
typedef ushort_t us8_t __attribute__((ext_vector_type(8)));

__device__ static inline ushort_t f2bf(float f) {
    union { float f; unsigned u; } v; v.f = f;
    unsigned r = v.u + 0x7FFFu + ((v.u >> 16) & 1u);   // RNE
    return (ushort_t)(r >> 16);
}
__device__ static inline float bf2f(ushort_t u) {
    union { unsigned u; float f; } v; v.u = ((unsigned)u) << 16;
    return v.f;
}

__device__ static inline void async_ld16(const ushort_t* g, ushort_t* l) {
    __builtin_amdgcn_global_load_lds(
        (const __attribute__((address_space(1))) unsigned int*)g,
        (__attribute__((address_space(3))) unsigned int*)l,
        16, 0, 0);
}

__device__ static inline void sbar() {
    __builtin_amdgcn_sched_barrier(0);
    __builtin_amdgcn_s_barrier();
    __builtin_amdgcn_sched_barrier(0);
}
#define VMCNT(n) do { asm volatile("s_waitcnt vmcnt(" #n ")" ::: "memory"); \
                      __builtin_amdgcn_sched_barrier(0); } while (0)
#define LGKM0() do { asm volatile("s_waitcnt lgkmcnt(0)" ::: "memory"); \
                     __builtin_amdgcn_sched_barrier(0); } while (0)

// XCD-aware bijective remap of 256 blocks (64 bm x 4 bn panels of 128x256).
// Round-robin dispatch -> xcd = bx % 8; each XCD gets 8 contiguous bm-panels
// x all 4 bn-panels (bn fastest): B (2 MB) resident in its L2, A reused.
__device__ static inline void swz256(int bx, int* bm, int* bn) {
    const int xcd = bx & 7, s = bx >> 3;
    *bm = (xcd * 8 + (s >> 2)) << 7;
    *bn = (s & 3) << 8;
}

#define ABUF (128*64)   // ushorts: A tile buffer (16 KiB)
#define BBUF (256*64)   // ushorts: B tile buffer (32 KiB)

// ---------------------------------------------------------------------------
// 128x256-tile bf16 GEMM core (round-3 known-good, used by gemm_out).
// 512 threads = 8 waves (2M x 4N), per-wave output 64x64, BK=64, K=1024.
// LDS: A[2][128][64] (32K) + B[2][256][64] (64K) = 96 KiB.
// T2 swizzle: LDS dest linear (global_load_lds); global SOURCE col pre-XOR'd;
// read slot XOR'd with row&7. SQ_LDS_BANK_CONFLICT = 0 (HW-verified).
// ---------------------------------------------------------------------------
__device__ static inline void gemm128_core(
    const ushort_t* __restrict__ A, const ushort_t* __restrict__ BT,
    ushort_t* As, ushort_t* Bs, int bm, int bn, int tid, f4_t acc[4][4])
{
    const int lane = tid & 63, w = tid >> 6;        // 8 waves
    const int wr = w >> 2, wc = w & 3;              // 2 x 4 wave grid
    const int quad = lane >> 4, l15 = lane & 15;
    const int lrow = lane >> 3;                     // 0..7
    const int kcol = ((lane & 7) ^ lrow) * 8;       // inverse-swizzled src col

    auto stB = [&](int t, int s) {                  // B tile: 4 loads/thread
        #pragma unroll
        for (int c = 0; c < 4; ++c) {
            const int r0 = c * 64 + w * 8;
            async_ld16(BT + (size_t)(bn + r0 + lrow) * DM + t * 64 + kcol,
                       &Bs[s * BBUF + r0 * 64]);
        }
    };
    auto stA1 = [&](int t, int s) {                 // A rows {[0,32),[64,96)}
        const int r0 = (w < 4) ? w * 8 : 32 + w * 8;
        async_ld16(A + (size_t)(bm + r0 + lrow) * DM + t * 64 + kcol,
                   &As[s * ABUF + r0 * 64]);
    };
    auto stA2 = [&](int t, int s) {                 // A rows {[32,64),[96,128)}
        const int r0 = (w < 4) ? 32 + w * 8 : 64 + w * 8;
        async_ld16(A + (size_t)(bm + r0 + lrow) * DM + t * 64 + kcol,
                   &As[s * ABUF + r0 * 64]);
    };

    auto loadB = [&](int s, bf8_t bf[2][4]) {
        #pragma unroll
        for (int ks = 0; ks < 2; ++ks) {
            const int slot8 = (((ks << 2) | quad) ^ (l15 & 7)) * 8;
            #pragma unroll
            for (int j = 0; j < 4; ++j) {
                const int row = wc * 64 + j * 16 + l15;
                bf[ks][j] = *(const bf8_t*)&Bs[s * BBUF + row * 64 + slot8];
            }
        }
    };
    auto loadA = [&](int s, int ih, bf8_t af[2][2]) {
        #pragma unroll
        for (int ks = 0; ks < 2; ++ks) {
            const int slot8 = (((ks << 2) | quad) ^ (l15 & 7)) * 8;
            #pragma unroll
            for (int i = 0; i < 2; ++i) {
                const int row = wr * 64 + (ih * 2 + i) * 16 + l15;
                af[ks][i] = *(const bf8_t*)&As[s * ABUF + row * 64 + slot8];
            }
        }
    };
    auto mfma16 = [&](int ih, bf8_t af[2][2], bf8_t bf[2][4]) {
        __builtin_amdgcn_s_setprio(1);
        #pragma unroll
        for (int ks = 0; ks < 2; ++ks)
            #pragma unroll
            for (int i = 0; i < 2; ++i)
                #pragma unroll
                for (int j = 0; j < 4; ++j)
                    acc[ih * 2 + i][j] = __builtin_amdgcn_mfma_f32_16x16x32_bf16(
                        af[ks][i], bf[ks][j], acc[ih * 2 + i][j], 0, 0, 0);
        __builtin_amdgcn_s_setprio(0);
    };

    stB(0, 0); stA1(0, 0);
    stA2(0, 0);
    stB(1, 1); stA1(1, 1);
    VMCNT(6);
    sbar();

    bf8_t bf[2][4], af[2][2];
    #pragma unroll 1
    for (int v = 0; v < 7; ++v) {
        const int u0 = 2 * v;
        loadB(0, bf); loadA(0, 0, af);
        stA2(u0 + 1, 1);
        VMCNT(6); sbar();
        mfma16(0, af, bf);
        sbar();
        loadA(0, 1, af);
        stB(u0 + 2, 0); stA1(u0 + 2, 0);
        VMCNT(6); sbar();
        mfma16(1, af, bf);
        sbar();
        loadB(1, bf); loadA(1, 0, af);
        stA2(u0 + 2, 0);
        VMCNT(6); sbar();
        mfma16(0, af, bf);
        sbar();
        loadA(1, 1, af);
        stB(u0 + 3, 1); stA1(u0 + 3, 1);
        VMCNT(6); sbar();
        mfma16(1, af, bf);
        sbar();
    }
    loadB(0, bf); loadA(0, 0, af);
    stA2(15, 1);
    VMCNT(6); sbar();
    mfma16(0, af, bf);
    sbar();
    loadA(0, 1, af);
    VMCNT(1); sbar();
    mfma16(1, af, bf);
    sbar();
    loadB(1, bf); loadA(1, 0, af);
    VMCNT(0); sbar();
    mfma16(0, af, bf);
    sbar();
    loadA(1, 1, af);
    mfma16(1, af, bf);
}

// ---------------------------------------------------------------------------
// prep: 4x transpose_cvt (z selects weight) + zero kmOrd.
// ---------------------------------------------------------------------------
__global__ __launch_bounds__(256) void prep_weights(
    const float* __restrict__ W0, const float* __restrict__ W1,
    const float* __restrict__ W2, const float* __restrict__ W3,
    ushort_t* __restrict__ WT, unsigned* __restrict__ kmOrd)
{
    if (blockIdx.z == 0 && blockIdx.x == 0 && blockIdx.y == 0 && threadIdx.x < 32)
        kmOrd[threadIdx.x] = 0u;
    const float* W = blockIdx.z == 0 ? W0 : (blockIdx.z == 1 ? W1 : (blockIdx.z == 2 ? W2 : W3));
    ushort_t* dst = WT + (size_t)blockIdx.z * DM * DM;
    __shared__ float t[32][33];
    const int k0 = blockIdx.x * 32, n0 = blockIdx.y * 32;
    const int tx = threadIdx.x & 31, ty = threadIdx.x >> 5;
    #pragma unroll
    for (int r = 0; r < 32; r += 8)
        t[ty + r][tx] = W[(size_t)(k0 + ty + r) * 1024 + n0 + tx];
    __syncthreads();
    #pragma unroll
    for (int r = 0; r < 32; r += 8)
        dst[(size_t)(n0 + ty + r) * 1024 + k0 + tx] = f2bf(t[tx][ty + r]);
}

// ---------------------------------------------------------------------------
// merged QKV GEMM with FUSED fp32->bf16 conversion (cvt_qkv eliminated).
// 128x256 tiles, 768 blocks = 3z x 256 (exactly 3 dispatch rounds).
// A path: reg-staged (T14 issue-early/write-late): 4x global_load_dwordx4 ->
// RNE f2bf (bit-identical to old cvt_qkv) -> 2x ds_write_b128 into swizzled
// slots. B path: global_load_lds (bf16 weights, pre-swizzled source).
// Ledger (per-thread, 4 VMEM ops per stage group, issue order A then B):
//   entry: issue A-regs(t+1)[4]; VMCNT(4) publishes B(t)[4]; sbar
//   mid:   stage B(t+1)[4] issued; VMCNT(4) publishes A-regs(t+1); cvt+write
//   end:   LGKM0 (A ds_writes drained); sbar
// Drain to 0 only in prologue and final tile. Swizzle both-sides: A write
// slot (aseg*2+c)^(arow&7) matches read slot ((ks<<2|quad))^(row&7).
// ---------------------------------------------------------------------------
__global__ __launch_bounds__(512, 2) void gemm_qkv(
    const float* __restrict__ Qf, const float* __restrict__ Kf,
    const float* __restrict__ Vf, const ushort_t* __restrict__ WT,
    const float* __restrict__ bq, const float* __restrict__ bk,
    const float* __restrict__ bv, ushort_t* __restrict__ Obase,
    unsigned* __restrict__ kmOrd)
{
    __shared__ ushort_t As[2 * ABUF];
    __shared__ ushort_t Bs[2 * BBUF];
    const int z = blockIdx.y;
    const float* A32 = z == 0 ? Qf : (z == 1 ? Kf : Vf);
    const ushort_t* BT = WT + (size_t)z * DM * DM;
    const float* bias = z == 0 ? bq : (z == 1 ? bk : bv);
    ushort_t* Cbf = Obase + (size_t)z * NROW * DM;

    const int tid = threadIdx.x;
    int bm, bn;
    swz256(blockIdx.x, &bm, &bn);
    const int lane = tid & 63, w = tid >> 6;
    const int wr = w >> 2, wc = w & 3;
    const int quad = lane >> 4, l15 = lane & 15;
    const int lrow = lane >> 3;
    const int kcol = ((lane & 7) ^ lrow) * 8;       // B: inverse-swz src col

    // A fp32 geometry: thread covers row arow, cols [aseg*16, aseg*16+16)
    const int arow = tid >> 2, aseg = tid & 3;
    const float* gA = A32 + (size_t)(bm + arow) * DM + aseg * 16;
    const int ws0 = ((aseg * 2) ^ (arow & 7)) * 8;      // swizzled write slots
    const int ws1 = ((aseg * 2 + 1) ^ (arow & 7)) * 8;

    f4_t a0, a1, a2, a3;
    auto issueA = [&](int t) {
        const f4_t* p = (const f4_t*)(gA + t * 64);
        a0 = p[0]; a1 = p[1]; a2 = p[2]; a3 = p[3];
    };
    auto cvtWriteA = [&](int sel) {
        us8_t o0, o1;
        o0[0]=f2bf(a0[0]); o0[1]=f2bf(a0[1]); o0[2]=f2bf(a0[2]); o0[3]=f2bf(a0[3]);
        o0[4]=f2bf(a1[0]); o0[5]=f2bf(a1[1]); o0[6]=f2bf(a1[2]); o0[7]=f2bf(a1[3]);
        o1[0]=f2bf(a2[0]); o1[1]=f2bf(a2[1]); o1[2]=f2bf(a2[2]); o1[3]=f2bf(a2[3]);
        o1[4]=f2bf(a3[0]); o1[5]=f2bf(a3[1]); o1[6]=f2bf(a3[2]); o1[7]=f2bf(a3[3]);
        *(us8_t*)&As[sel * ABUF + arow * 64 + ws0] = o0;
        *(us8_t*)&As[sel * ABUF + arow * 64 + ws1] = o1;
    };
    auto stB = [&](int t, int s) {                  // 4 gload_lds per thread
        #pragma unroll
        for (int c = 0; c < 4; ++c) {
            const int r0 = c * 64 + w * 8;
            async_ld16(BT + (size_t)(bn + r0 + lrow) * DM + t * 64 + kcol,
                       &Bs[s * BBUF + r0 * 64]);
        }
    };

    bf8_t af[4], bf[4];
    auto rdFrags = [&](int s, int ks) {
        const int slot8 = (((ks << 2) | quad) ^ (l15 & 7)) * 8;
        #pragma unroll
        for (int i = 0; i < 4; ++i)
            af[i] = *(const bf8_t*)&As[s * ABUF + (wr * 64 + i * 16 + l15) * 64 + slot8];
        #pragma unroll
        for (int j = 0; j < 4; ++j)
            bf[j] = *(const bf8_t*)&Bs[s * BBUF + (wc * 64 + j * 16 + l15) * 64 + slot8];
    };
    f4_t acc[4][4] = {};
    auto mm = [&]() {
        __builtin_amdgcn_s_setprio(1);
        #pragma unroll
        for (int i = 0; i < 4; ++i)
            #pragma unroll
            for (int j = 0; j < 4; ++j)
                acc[i][j] = __builtin_amdgcn_mfma_f32_16x16x32_bf16(
                    af[i], bf[j], acc[i][j], 0, 0, 0);
        __builtin_amdgcn_s_setprio(0);
    };

    // ---- prologue: tile 0 A via regs (full drain, one-time); B(0) issued ----
    issueA(0);
    VMCNT(0);
    cvtWriteA(0);
    stB(0, 0);
    LGKM0();            // own As[0] writes drained before first barrier

    // ---- main loop t = 0..14 (tile 15 peeled) ----
    #pragma unroll 1
    for (int t = 0; t < 15; ++t) {
        const int s = t & 1;
        issueA(t + 1);                 // 4 vmem reg-loads (newest)
        VMCNT(4);                      // publishes B(t); buf s complete
        sbar();
        rdFrags(s, 0);
        stB(t + 1, s ^ 1);             // 4 gload_lds (newest)
        mm();
        VMCNT(4);                      // publishes A-regs(t+1)
        cvtWriteA(s ^ 1);
        rdFrags(s, 1);
        mm();
        LGKM0();                       // A ds_writes (and reads) drained
        sbar();
    }
    // ---- tile 15 (s=1): only B(15) outstanding ----
    VMCNT(0);
    sbar();
    rdFrags(1, 0);
    mm();
    rdFrags(1, 1);
    mm();

    // ---- epilogue ----
    float mx = -3.4e38f;
    #pragma unroll
    for (int j = 0; j < 4; ++j) {
        const int col = bn + wc * 64 + j * 16 + l15;
        const float bb = bias[col];
        #pragma unroll
        for (int i = 0; i < 4; ++i) {
            const int row0 = bm + wr * 64 + i * 16 + quad * 4;
            #pragma unroll
            for (int r = 0; r < 4; ++r) {
                float v = acc[i][j][r] + bb;
                mx = fmaxf(mx, v);
                Cbf[(size_t)(row0 + r) * DM + col] = f2bf(v);
            }
        }
    }
    if (z == 1) {
        // wave covers one (b,h): rows bm..bm+127 (one b), cols bn+wc*64..+64.
        #pragma unroll
        for (int off = 32; off; off >>= 1) mx = fmaxf(mx, __shfl_xor(mx, off));
        if (lane == 0) {
            const int b = bm >> 12;
            const int h = (bn + wc * 64) >> 6;
            unsigned ub = __float_as_uint(mx);
            unsigned enc = (ub & 0x80000000u) ? ~ub : (ub | 0x80000000u);
            atomicMax(&kmOrd[b * NH + h], enc);
        }
    }
}

// ---------------------------------------------------------------------------
// final GEMM (128x256 tiles, 256 blocks): obf @ WoT + bo -> fp32 d_out
// ---------------------------------------------------------------------------
__global__ __launch_bounds__(512, 2) void gemm_out(
    const ushort_t* __restrict__ A, const ushort_t* __restrict__ BT,
    const float* __restrict__ bias, float* __restrict__ C)
{
    __shared__ ushort_t As[2 * ABUF];
    __shared__ ushort_t Bs[2 * BBUF];
    const int tid = threadIdx.x;
    int bm, bn;
    swz256(blockIdx.x, &bm, &bn);
    const int lane = tid & 63, w = tid >> 6;
    const int wr = w >> 2, wc = w & 3;
    const int quad = lane >> 4, l15 = lane & 15;

    f4_t acc[4][4] = {};
    gemm128_core(A, BT, As, Bs, bm, bn, tid, acc);

    #pragma unroll
    for (int j = 0; j < 4; ++j) {
        const int col = bn + wc * 64 + j * 16 + l15;
        const float bb = bias[col];
        #pragma unroll
        for (int i = 0; i < 4; ++i) {
            const int row0 = bm + wr * 64 + i * 16 + quad * 4;
            #pragma unroll
            for (int r = 0; r < 4; ++r)
                C[(size_t)(row0 + r) * DM + col] = acc[i][j][r] + bb;
        }
    }
}

// ---------------------------------------------------------------------------
// FAVOR feature map for K (MFMA), in-place on bf16 X [RQ,64].
// ---------------------------------------------------------------------------
__global__ __launch_bounds__(256) void favor_k_mfma(
    ushort_t* __restrict__ X, const float* __restrict__ Wf,
    const unsigned* __restrict__ kmOrd)
{
    __shared__ ushort_t Xs[64 * PITCH];
    __shared__ ushort_t Ws[64 * PITCH];
    __shared__ float ssp[64][4];
    __shared__ float diag[64], mxr[64];
    const int tid = threadIdx.x;
    const int lane = tid & 63, w = tid >> 6;
    const int quad = lane >> 4, l15 = lane & 15;
    const int rbase = blockIdx.x * 64;

    #pragma unroll
    for (int r = 0; r < 2; ++r) {
        int idx = tid + r * 256;
        int row = idx >> 3, ch = idx & 7;
        *(us8_t*)&Xs[row * PITCH + ch * 8] =
            *(const us8_t*)&X[(size_t)(rbase + row) * 64 + ch * 8];
    }
    const float4* Wf4 = (const float4*)Wf;
    #pragma unroll
    for (int i = 0; i < 4; ++i) {
        int f4i = tid + i * 256;
        int row = f4i >> 4, q4 = f4i & 15;
        float4 wv = Wf4[f4i];
        Ws[row * PITCH + q4 * 4 + 0] = f2bf(DN * wv.x);
        Ws[row * PITCH + q4 * 4 + 1] = f2bf(DN * wv.y);
        Ws[row * PITCH + q4 * 4 + 2] = f2bf(DN * wv.z);
        Ws[row * PITCH + q4 * 4 + 3] = f2bf(DN * wv.w);
    }
    __syncthreads();

    {
        const int row = tid >> 2, seg = tid & 3;
        const us8_t* xp = (const us8_t*)&Xs[row * PITCH + seg * 16];
        us8_t a = xp[0], b2 = xp[1];
        float ss = 0.f;
        #pragma unroll
        for (int j = 0; j < 8; ++j) {
            float x0 = bf2f(a[j]), x1 = bf2f(b2[j]);
            ss += x0 * x0 + x1 * x1;
        }
        ssp[row][seg] = ss;
    }
    __syncthreads();
    if (tid < 64) {
        diag[tid] = (ssp[tid][0] + ssp[tid][1] + ssp[tid][2] + ssp[tid][3]) * DIAG_SCALE;
        int rg = rbase + tid;
        int h = rg & (NH - 1);
        int b = rg >> 16;
        unsigned u = kmOrd[b * NH + h];
        unsigned bits = (u & 0x80000000u) ? (u & 0x7FFFFFFFu) : ~u;
        mxr[tid] = DN * __uint_as_float(bits);
    }
    __syncthreads();

    bf8_t xf[2];
    #pragma unroll
    for (int ks = 0; ks < 2; ++ks)
        xf[ks] = *(const bf8_t*)&Xs[(w * 16 + l15) * PITCH + ks * 32 + quad * 8];
    f4_t acc[4] = {};
    #pragma unroll
    for (int dt = 0; dt < 4; ++dt)
        #pragma unroll
        for (int ks = 0; ks < 2; ++ks) {
            bf8_t wfr = *(const bf8_t*)&Ws[(dt * 16 + l15) * PITCH + ks * 32 + quad * 8];
            acc[dt] = __builtin_amdgcn_mfma_f32_16x16x32_bf16(xf[ks], wfr, acc[dt], 0, 0, 0);
        }
    __syncthreads();

    #pragma unroll
    for (int r = 0; r < 4; ++r) {
        int row = w * 16 + quad * 4 + r;
        float d_ = diag[row], m_ = mxr[row];
        #pragma unroll
        for (int dt = 0; dt < 4; ++dt) {
            float e = acc[dt][r] - d_ - m_ + 1e-8f;
            X[(size_t)(rbase + row) * 64 + dt * 16 + l15] = f2bf(INV_SQRT_M * expf(e));
        }
    }
}

// ---------------------------------------------------------------------------
// chunk_sums (MFMA): S^T[d][m] = sum_t V[t][d]*K[t][m]; row 64 = z[m]. bf16 out.
// ---------------------------------------------------------------------------
__global__ __launch_bounds__(256) void chunk_sums_mfma(
    const ushort_t* __restrict__ Kbf, const ushort_t* __restrict__ Vbf,
    ushort_t* __restrict__ ST)
{
    const int bx = blockIdx.x;
    const int c = bx & 63, h = (bx >> 6) & 15, b = bx >> 10;
    __shared__ ushort_t Kt[64 * PITCH];
    __shared__ ushort_t Vt[80 * PITCH];
    const int tid = threadIdx.x;
    const int lane = tid & 63, w = tid >> 6;
    const int quad = lane >> 4, l15 = lane & 15;

    const size_t gbase = ((size_t)(b * SEQ + c * CT)) * DM + h * MD;
    #pragma unroll
    for (int r = 0; r < 2; ++r) {
        int ch = w + r * 4;
        int t = lane;
        us8_t kv = *(const us8_t*)&Kbf[gbase + (size_t)t * DM + ch * 8];
        us8_t vv = *(const us8_t*)&Vbf[gbase + (size_t)t * DM + ch * 8];
        #pragma unroll
        for (int j = 0; j < 8; ++j) {
            Kt[(ch * 8 + j) * PITCH + t] = kv[j];
            Vt[(ch * 8 + j) * PITCH + t] = vv[j];
        }
    }
    if (tid < 64) Vt[64 * PITCH + tid] = (ushort_t)0x3F80;
    __syncthreads();

    ushort_t* Sg = ST + (size_t)((b * NH + h) * NCHUNK + c) * STSZ;

    bf8_t vf[2];
    #pragma unroll
    for (int ks = 0; ks < 2; ++ks)
        vf[ks] = *(const bf8_t*)&Vt[(w * 16 + l15) * PITCH + ks * 32 + quad * 8];
    f4_t acc[4] = {};
    #pragma unroll
    for (int mt = 0; mt < 4; ++mt)
        #pragma unroll
        for (int ks = 0; ks < 2; ++ks) {
            bf8_t kf = *(const bf8_t*)&Kt[(mt * 16 + l15) * PITCH + ks * 32 + quad * 8];
            acc[mt] = __builtin_amdgcn_mfma_f32_16x16x32_bf16(vf[ks], kf, acc[mt], 0, 0, 0);
        }
    #pragma unroll
    for (int mt = 0; mt < 4; ++mt)
        #pragma unroll
        for (int r = 0; r < 4; ++r)
            Sg[(w * 16 + quad * 4 + r) * 64 + mt * 16 + l15] = f2bf(acc[mt][r]);

    if (w == 0) {
        bf8_t vf4[2];
        #pragma unroll
        for (int ks = 0; ks < 2; ++ks)
            vf4[ks] = *(const bf8_t*)&Vt[(64 + l15) * PITCH + ks * 32 + quad * 8];
        f4_t accz[4] = {};
        #pragma unroll
        for (int mt = 0; mt < 4; ++mt)
            #pragma unroll
            for (int ks = 0; ks < 2; ++ks) {
                bf8_t kf = *(const bf8_t*)&Kt[(mt * 16 + l15) * PITCH + ks * 32 + quad * 8];
                accz[mt] = __builtin_amdgcn_mfma_f32_16x16x32_bf16(vf4[ks], kf, accz[mt], 0, 0, 0);
            }
        if (quad == 0) {
            #pragma unroll
            for (int mt = 0; mt < 4; ++mt)
                Sg[64 * 64 + mt * 16 + l15] = f2bf(accz[mt][0]);
        }
    }
}

// ---------------------------------------------------------------------------
// Exclusive prefix over chunks on bf16 ST; register-pipelined.
// ---------------------------------------------------------------------------
__global__ __launch_bounds__(256) void prefix_scan_st(ushort_t* __restrict__ ST)
{
    const int sb = blockIdx.x / 17;
    const int e = (blockIdx.x % 17) * 256 + threadIdx.x;
    if (e >= STSZ) return;
    ushort_t* p = ST + (size_t)sb * NCHUNK * STSZ + e;
    ushort_t v[NCHUNK];
    #pragma unroll
    for (int c = 0; c < NCHUNK; ++c) v[c] = p[(size_t)c * STSZ];
    float run = 0.f;
    #pragma unroll
    for (int c = 0; c < NCHUNK; ++c) {
        float cur = bf2f(v[c]);
        p[(size_t)c * STSZ] = f2bf(run);
        run += cur;
    }
}

// ---------------------------------------------------------------------------
// intra-chunk causal attention (MFMA) with inline FAVOR-q.
// ---------------------------------------------------------------------------
__global__ __launch_bounds__(256) void intra_attn_mfma(
    const ushort_t* __restrict__ Qraw, const ushort_t* __restrict__ Kbf,
    const ushort_t* __restrict__ Vbf, const ushort_t* __restrict__ ST,
    const float* __restrict__ Wfq, ushort_t* __restrict__ Obf)
{
    const int bx = blockIdx.x;
    const int c = bx & 63, h = (bx >> 6) & 15, b = bx >> 10;
    __shared__ ushort_t Qs[64 * PITCH];
    __shared__ ushort_t Ks[64 * PITCH];
    __shared__ ushort_t Vt[80 * PITCH];
    __shared__ ushort_t St[80 * PITCH];
    __shared__ ushort_t Ws[64 * PITCH];
    __shared__ float ssp[64][4];
    __shared__ float mxp[64][4];
    __shared__ float diag[64], mxr[64], dens[64];
    const int tid = threadIdx.x;
    const int lane = tid & 63, w = tid >> 6;
    const int quad = lane >> 4, l15 = lane & 15;

    const size_t gbase = ((size_t)(b * SEQ + c * CT)) * DM + h * MD;

    #pragma unroll
    for (int r = 0; r < 2; ++r) {
        int idx = tid + r * 256;
        int row = idx >> 3, ch = idx & 7;
        us8_t qv = *(const us8_t*)&Qraw[gbase + (size_t)row * DM + ch * 8];
        us8_t kv = *(const us8_t*)&Kbf[gbase + (size_t)row * DM + ch * 8];
        *(us8_t*)&Qs[row * PITCH + ch * 8] = qv;
        *(us8_t*)&Ks[row * PITCH + ch * 8] = kv;
    }
    #pragma unroll
    for (int r = 0; r < 2; ++r) {
        int ch = w + r * 4;
        int t = lane;
        us8_t vv = *(const us8_t*)&Vbf[gbase + (size_t)t * DM + ch * 8];
        #pragma unroll
        for (int j = 0; j < 8; ++j) Vt[(ch * 8 + j) * PITCH + t] = vv[j];
    }
    #pragma unroll
    for (int r = 0; r < 4; ++r) {
        int idx = tid + r * 256;
        int row = 64 + (idx >> 6), t = idx & 63;
        Vt[row * PITCH + t] = (row == 64) ? (ushort_t)0x3F80 : (ushort_t)0;
    }
    const us8_t* Sg8 = (const us8_t*)(ST + (size_t)((b * NH + h) * NCHUNK + c) * STSZ);
    #pragma unroll
    for (int r = 0; r < 3; ++r) {
        int idx = tid + r * 256;
        if (idx < 520) {
            int d = idx >> 3, mo = (idx & 7) * 8;
            *(us8_t*)&St[d * PITCH + mo] = Sg8[idx];
        }
        int idx2 = idx - 520;
        if (idx2 >= 0 && idx2 < 120) {
            int row = 65 + (idx2 >> 3), mo = (idx2 & 7) * 8;
            us8_t z = {};
            *(us8_t*)&St[row * PITCH + mo] = z;
        }
    }
    const float4* Wf4 = (const float4*)Wfq;
    #pragma unroll
    for (int i = 0; i < 4; ++i) {
        int f4i = tid + i * 256;
        int row = f4i >> 4, q4 = f4i & 15;
        float4 wv = Wf4[f4i];
        Ws[row * PITCH + q4 * 4 + 0] = f2bf(DN * wv.x);
        Ws[row * PITCH + q4 * 4 + 1] = f2bf(DN * wv.y);
        Ws[row * PITCH + q4 * 4 + 2] = f2bf(DN * wv.z);
        Ws[row * PITCH + q4 * 4 + 3] = f2bf(DN * wv.w);
    }
    __syncthreads();

    {
        const int row = tid >> 2, seg = tid & 3;
        const us8_t* xp = (const us8_t*)&Qs[row * PITCH + seg * 16];
        us8_t a = xp[0], b2 = xp[1];
        float ss = 0.f, mx = -3.4e38f;
        #pragma unroll
        for (int j = 0; j < 8; ++j) {
            float x0 = bf2f(a[j]), x1 = bf2f(b2[j]);
            ss += x0 * x0 + x1 * x1;
            mx = fmaxf(mx, fmaxf(x0, x1));
        }
        ssp[row][seg] = ss;
        mxp[row][seg] = mx;
    }
    __syncthreads();
    if (tid < 64) {
        diag[tid] = (ssp[tid][0] + ssp[tid][1] + ssp[tid][2] + ssp[tid][3]) * DIAG_SCALE;
        mxr[tid] = DN * fmaxf(fmaxf(mxp[tid][0], mxp[tid][1]),
                              fmaxf(mxp[tid][2], mxp[tid][3]));
    }
    __syncthreads();

    {
        bf8_t xf[2];
        #pragma unroll
        for (int ks = 0; ks < 2; ++ks)
            xf[ks] = *(const bf8_t*)&Qs[(w * 16 + l15) * PITCH + ks * 32 + quad * 8];
        f4_t facc[4] = {};
        #pragma unroll
        for (int dt = 0; dt < 4; ++dt)
            #pragma unroll
            for (int ks = 0; ks < 2; ++ks) {
                bf8_t wfr = *(const bf8_t*)&Ws[(dt * 16 + l15) * PITCH + ks * 32 + quad * 8];
                facc[dt] = __builtin_amdgcn_mfma_f32_16x16x32_bf16(xf[ks], wfr, facc[dt], 0, 0, 0);
            }
        __syncthreads();
        #pragma unroll
        for (int r = 0; r < 4; ++r) {
            int row = w * 16 + quad * 4 + r;
            float d_ = diag[row], m_ = mxr[row];
            #pragma unroll
            for (int dt = 0; dt < 4; ++dt) {
                float e = facc[dt][r] - d_ - m_ + 1e-8f;
                Qs[row * PITCH + dt * 16 + l15] = f2bf(INV_SQRT_M * expf(e));
            }
        }
    }
    __syncthreads();

    bf8_t qf[2];
    #pragma unroll
    for (int ks = 0; ks < 2; ++ks)
        qf[ks] = *(const bf8_t*)&Qs[(w * 16 + l15) * PITCH + ks * 32 + quad * 8];
    f4_t accA[4] = {};
    #pragma unroll
    for (int jt = 0; jt < 4; ++jt)
        #pragma unroll
        for (int ks = 0; ks < 2; ++ks) {
            bf8_t kf = *(const bf8_t*)&Ks[(jt * 16 + l15) * PITCH + ks * 32 + quad * 8];
            accA[jt] = __builtin_amdgcn_mfma_f32_16x16x32_bf16(qf[ks], kf, accA[jt], 0, 0, 0);
        }
    __syncthreads();
    #pragma unroll
    for (int jt = 0; jt < 4; ++jt) {
        int j = jt * 16 + l15;
        #pragma unroll
        for (int r = 0; r < 4; ++r) {
            int i = w * 16 + quad * 4 + r;
            float a = (j <= i) ? accA[jt][r] : 0.f;
            Ks[i * PITCH + j] = f2bf(a);
        }
    }
    __syncthreads();

    bf8_t af[2];
    #pragma unroll
    for (int ks = 0; ks < 2; ++ks)
        af[ks] = *(const bf8_t*)&Ks[(w * 16 + l15) * PITCH + ks * 32 + quad * 8];
    f4_t acc[5] = {};
    #pragma unroll
    for (int dt = 0; dt < 5; ++dt)
        #pragma unroll
        for (int ks = 0; ks < 2; ++ks) {
            bf8_t sf = *(const bf8_t*)&St[(dt * 16 + l15) * PITCH + ks * 32 + quad * 8];
            acc[dt] = __builtin_amdgcn_mfma_f32_16x16x32_bf16(qf[ks], sf, acc[dt], 0, 0, 0);
            bf8_t vf = *(const bf8_t*)&Vt[(dt * 16 + l15) * PITCH + ks * 32 + quad * 8];
            acc[dt] = __builtin_amdgcn_mfma_f32_16x16x32_bf16(af[ks], vf, acc[dt], 0, 0, 0);
        }
    if (l15 == 0) {
        #pragma unroll
        for (int r = 0; r < 4; ++r) dens[w * 16 + quad * 4 + r] = acc[4][r];
    }
    __syncthreads();

    #pragma unroll
    for (int r = 0; r < 4; ++r) {
        int i = w * 16 + quad * 4 + r;
        float inv = 1.0f / dens[i];
        #pragma unroll
        for (int dt = 0; dt < 4; ++dt)
            Obf[gbase + (size_t)i * DM + dt * 16 + l15] = f2bf(acc[dt][r] * inv);
    }
}

// ---------------------------------------------------------------------------
extern "C" void kernel_launch(void* const* d_in, const int* in_sizes, int n_in,
                              void* d_out, int out_size, void* d_ws, size_t ws_size,
                              hipStream_t stream)
{
    const float* queries = (const float*)d_in[0];
    const float* keys    = (const float*)d_in[1];
    const float* values  = (const float*)d_in[2];
    const float* Wq = (const float*)d_in[3];  const float* bq = (const float*)d_in[4];
    const float* Wk = (const float*)d_in[5];  const float* bk = (const float*)d_in[6];
    const float* Wv = (const float*)d_in[7];  const float* bv = (const float*)d_in[8];
    const float* Wo = (const float*)d_in[9];  const float* bo = (const float*)d_in[10];
    const float* Wfq = (const float*)d_in[11];
    const float* Wfk = (const float*)d_in[12];

    char* ws = (char*)d_ws;
    unsigned* kmOrd = (unsigned*)ws;                       // [32] (pad)
    ushort_t* STb = (ushort_t*)(ws + 256);                 // [32,64,65*64] bf16
    ushort_t* qbf = STb + (size_t)32 * NCHUNK * STSZ;      // qkv bf16 GEMM outputs
    ushort_t* kbf = qbf + (size_t)NROW * DM;
    ushort_t* vbf = kbf + (size_t)NROW * DM;
    ushort_t* obf = vbf + (size_t)NROW * DM;               // bf16 attn out
    ushort_t* wT  = obf + (size_t)NROW * DM;               // 4 x [1024,1024] bf16
    ushort_t* WoT = wT + (size_t)3 * DM * DM;

    prep_weights<<<dim3(32, 32, 4), 256, 0, stream>>>(Wq, Wk, Wv, Wo, wT, kmOrd);

    gemm_qkv<<<dim3(256, 3), 512, 0, stream>>>(queries, keys, values, wT,
                                               bq, bk, bv, qbf, kmOrd);

    favor_k_mfma<<<RQ / 64, 256, 0, stream>>>(kbf, Wfk, kmOrd);

    chunk_sums_mfma<<<BATCH * NH * NCHUNK, 256, 0, stream>>>(kbf, vbf, STb);
    prefix_scan_st<<<32 * 17, 256, 0, stream>>>(STb);
    intra_attn_mfma<<<BATCH * NH * NCHUNK, 256, 0, stream>>>(qbf, kbf, vbf, STb, Wfq, obf);

    gemm_out<<<256, 512, 0, stream>>>(obf, WoT, bo, (float*)d_out);
}

// Round 7
// 313.341 us; speedup vs baseline: 1.0935x; 1.0475x over previous
//
#include <hip/hip_runtime.h>
#include <math.h>

// Problem constants: B=2, L=4096, d_model=1024, H=16, M=D=64
#define BATCH 2
#define SEQ   4096
#define DM    1024
#define NH    16
#define MD    64
#define NROW  (BATCH*SEQ)     // 8192
#define RQ    (BATCH*SEQ*NH)  // 131072
#define NCHUNK 64
#define CT     64
#define DN    0.35355339059327373f
#define INV_SQRT_M 0.125f
#define PITCH 72              // ushort row pitch for bf16 LDS tiles
#define STSZ  (65*64)         // per-(bh,c) S^T chunk: rows d=0..64 (row 64 = z)
#define DIAG_SCALE (0.125f * 0.0625f)   // DN^2 * 0.5*DN^2

typedef unsigned short ushort_t;
typedef short bf8_t __attribute__((ext_vector_type(8)));
typedef float f4_t  __attribute__((ext_vector_type(4)));
typedef ushort_t us8_t __attribute__((ext_vector_type(8)));

__device__ static inline ushort_t f2bf(float f) {
    union { float f; unsigned u; } v; v.f = f;
    unsigned r = v.u + 0x7FFFu + ((v.u >> 16) & 1u);   // RNE
    return (ushort_t)(r >> 16);
}
__device__ static inline float bf2f(ushort_t u) {
    union { unsigned u; float f; } v; v.u = ((unsigned)u) << 16;
    return v.f;
}

__device__ static inline void async_ld16(const ushort_t* g, ushort_t* l) {
    __builtin_amdgcn_global_load_lds(
        (const __attribute__((address_space(1))) unsigned int*)g,
        (__attribute__((address_space(3))) unsigned int*)l,
        16, 0, 0);
}

__device__ static inline void sbar() {
    __builtin_amdgcn_sched_barrier(0);
    __builtin_amdgcn_s_barrier();
    __builtin_amdgcn_sched_barrier(0);
}
#define VMCNT(n) do { asm volatile("s_waitcnt vmcnt(" #n ")" ::: "memory"); \
                      __builtin_amdgcn_sched_barrier(0); } while (0)

// XCD-aware bijective remap of 256 blocks (64 bm x 4 bn panels of 128x256).
__device__ static inline void swz256(int bx, int* bm, int* bn) {
    const int xcd = bx & 7, s = bx >> 3;
    *bm = (xcd * 8 + (s >> 2)) << 7;
    *bn = (s & 3) << 8;
}

#define ABUF (128*64)   // ushorts: A tile buffer (16 KiB)
#define BBUF (256*64)   // ushorts: B tile buffer (32 KiB)

// ---------------------------------------------------------------------------
// 128x256-tile bf16 GEMM core (round-3 known-good).
// 512 threads = 8 waves (2M x 4N), per-wave output 64x64, BK=64, K=1024.
// LDS: A[2][128][64] (32K) + B[2][256][64] (64K) = 96 KiB.
// T2 swizzle: LDS dest linear (global_load_lds); global SOURCE col pre-XOR'd;
// read slot XOR'd with row&7. SQ_LDS_BANK_CONFLICT = 0 (HW-verified).
// ---------------------------------------------------------------------------
__device__ static inline void gemm128_core(
    const ushort_t* __restrict__ A, const ushort_t* __restrict__ BT,
    ushort_t* As, ushort_t* Bs, int bm, int bn, int tid, f4_t acc[4][4])
{
    const int lane = tid & 63, w = tid >> 6;        // 8 waves
    const int wr = w >> 2, wc = w & 3;              // 2 x 4 wave grid
    const int quad = lane >> 4, l15 = lane & 15;
    const int lrow = lane >> 3;                     // 0..7
    const int kcol = ((lane & 7) ^ lrow) * 8;       // inverse-swizzled src col

    auto stB = [&](int t, int s) {                  // B tile: 4 loads/thread
        #pragma unroll
        for (int c = 0; c < 4; ++c) {
            const int r0 = c * 64 + w * 8;
            async_ld16(BT + (size_t)(bn + r0 + lrow) * DM + t * 64 + kcol,
                       &Bs[s * BBUF + r0 * 64]);
        }
    };
    auto stA1 = [&](int t, int s) {                 // A rows {[0,32),[64,96)}
        const int r0 = (w < 4) ? w * 8 : 32 + w * 8;
        async_ld16(A + (size_t)(bm + r0 + lrow) * DM + t * 64 + kcol,
                   &As[s * ABUF + r0 * 64]);
    };
    auto stA2 = [&](int t, int s) {                 // A rows {[32,64),[96,128)}
        const int r0 = (w < 4) ? 32 + w * 8 : 64 + w * 8;
        async_ld16(A + (size_t)(bm + r0 + lrow) * DM + t * 64 + kcol,
                   &As[s * ABUF + r0 * 64]);
    };

    auto loadB = [&](int s, bf8_t bf[2][4]) {
        #pragma unroll
        for (int ks = 0; ks < 2; ++ks) {
            const int slot8 = (((ks << 2) | quad) ^ (l15 & 7)) * 8;
            #pragma unroll
            for (int j = 0; j < 4; ++j) {
                const int row = wc * 64 + j * 16 + l15;
                bf[ks][j] = *(const bf8_t*)&Bs[s * BBUF + row * 64 + slot8];
            }
        }
    };
    auto loadA = [&](int s, int ih, bf8_t af[2][2]) {
        #pragma unroll
        for (int ks = 0; ks < 2; ++ks) {
            const int slot8 = (((ks << 2) | quad) ^ (l15 & 7)) * 8;
            #pragma unroll
            for (int i = 0; i < 2; ++i) {
                const int row = wr * 64 + (ih * 2 + i) * 16 + l15;
                af[ks][i] = *(const bf8_t*)&As[s * ABUF + row * 64 + slot8];
            }
        }
    };
    auto mfma16 = [&](int ih, bf8_t af[2][2], bf8_t bf[2][4]) {
        __builtin_amdgcn_s_setprio(1);
        #pragma unroll
        for (int ks = 0; ks < 2; ++ks)
            #pragma unroll
            for (int i = 0; i < 2; ++i)
                #pragma unroll
                for (int j = 0; j < 4; ++j)
                    acc[ih * 2 + i][j] = __builtin_amdgcn_mfma_f32_16x16x32_bf16(
                        af[ks][i], bf[ks][j], acc[ih * 2 + i][j], 0, 0, 0);
        __builtin_amdgcn_s_setprio(0);
    };

    stB(0, 0); stA1(0, 0);
    stA2(0, 0);
    stB(1, 1); stA1(1, 1);
    VMCNT(6);
    sbar();

    bf8_t bf[2][4], af[2][2];
    #pragma unroll 1
    for (int v = 0; v < 7; ++v) {
        const int u0 = 2 * v;
        loadB(0, bf); loadA(0, 0, af);
        stA2(u0 + 1, 1);
        VMCNT(6); sbar();
        mfma16(0, af, bf);
        sbar();
        loadA(0, 1, af);
        stB(u0 + 2, 0); stA1(u0 + 2, 0);
        VMCNT(6); sbar();
        mfma16(1, af, bf);
        sbar();
        loadB(1, bf); loadA(1, 0, af);
        stA2(u0 + 2, 0);
        VMCNT(6); sbar();
        mfma16(0, af, bf);
        sbar();
        loadA(1, 1, af);
        stB(u0 + 3, 1); stA1(u0 + 3, 1);
        VMCNT(6); sbar();
        mfma16(1, af, bf);
        sbar();
    }
    loadB(0, bf); loadA(0, 0, af);
    stA2(15, 1);
    VMCNT(6); sbar();
    mfma16(0, af, bf);
    sbar();
    loadA(0, 1, af);
    VMCNT(1); sbar();
    mfma16(1, af, bf);
    sbar();
    loadB(1, bf); loadA(1, 0, af);
    VMCNT(0); sbar();
    mfma16(0, af, bf);
    sbar();
    loadA(1, 1, af);
    mfma16(1, af, bf);
}

// ---------------------------------------------------------------------------
// prep: 4x transpose_cvt (z selects weight) + zero kmOrd.
// ---------------------------------------------------------------------------
__global__ __launch_bounds__(256) void prep_weights(
    const float* __restrict__ W0, const float* __restrict__ W1,
    const float* __restrict__ W2, const float* __restrict__ W3,
    ushort_t* __restrict__ WT, unsigned* __restrict__ kmOrd)
{
    if (blockIdx.z == 0 && blockIdx.x == 0 && blockIdx.y == 0 && threadIdx.x < 32)
        kmOrd[threadIdx.x] = 0u;
    const float* W = blockIdx.z == 0 ? W0 : (blockIdx.z == 1 ? W1 : (blockIdx.z == 2 ? W2 : W3));
    ushort_t* dst = WT + (size_t)blockIdx.z * DM * DM;
    __shared__ float t[32][33];
    const int k0 = blockIdx.x * 32, n0 = blockIdx.y * 32;
    const int tx = threadIdx.x & 31, ty = threadIdx.x >> 5;
    #pragma unroll
    for (int r = 0; r < 32; r += 8)
        t[ty + r][tx] = W[(size_t)(k0 + ty + r) * 1024 + n0 + tx];
    __syncthreads();
    #pragma unroll
    for (int r = 0; r < 32; r += 8)
        dst[(size_t)(n0 + ty + r) * 1024 + k0 + tx] = f2bf(t[tx][ty + r]);
}

// ---------------------------------------------------------------------------
// fused fp32 -> bf16 convert for q,k,v
// ---------------------------------------------------------------------------
__global__ __launch_bounds__(256) void cvt_qkv(
    const float* __restrict__ Q, const float* __restrict__ K,
    const float* __restrict__ V, ushort_t* __restrict__ Y)
{
    const int y = blockIdx.y;
    const float* X = y == 0 ? Q : (y == 1 ? K : V);
    ushort_t* dst = Y + (size_t)y * NROW * DM;
    int i = blockIdx.x * 256 + threadIdx.x;
    const float4* X4 = (const float4*)X;
    float4 a = X4[i * 2], b = X4[i * 2 + 1];
    us8_t o;
    o[0]=f2bf(a.x); o[1]=f2bf(a.y); o[2]=f2bf(a.z); o[3]=f2bf(a.w);
    o[4]=f2bf(b.x); o[5]=f2bf(b.y); o[6]=f2bf(b.z); o[7]=f2bf(b.w);
    *(us8_t*)&dst[i * 8] = o;
}

// ---------------------------------------------------------------------------
// merged QKV GEMM (128x256 tiles): blockIdx.y selects z slice.
// z==1 (keys) folds per-(b,h) output max into kmOrd via ordered-uint atomicMax.
// ---------------------------------------------------------------------------
__global__ __launch_bounds__(512, 2) void gemm_qkv(
    const ushort_t* __restrict__ Xc, const ushort_t* __restrict__ WT,
    const float* __restrict__ bq, const float* __restrict__ bk,
    const float* __restrict__ bv, ushort_t* __restrict__ Obase,
    unsigned* __restrict__ kmOrd)
{
    __shared__ ushort_t As[2 * ABUF];
    __shared__ ushort_t Bs[2 * BBUF];
    const int z = blockIdx.y;
    const ushort_t* A  = Xc + (size_t)z * NROW * DM;
    const ushort_t* BT = WT + (size_t)z * DM * DM;
    const float* bias = z == 0 ? bq : (z == 1 ? bk : bv);
    ushort_t* Cbf = Obase + (size_t)z * NROW * DM;

    const int tid = threadIdx.x;
    int bm, bn;
    swz256(blockIdx.x, &bm, &bn);
    const int lane = tid & 63, w = tid >> 6;
    const int wr = w >> 2, wc = w & 3;
    const int quad = lane >> 4, l15 = lane & 15;

    f4_t acc[4][4] = {};
    gemm128_core(A, BT, As, Bs, bm, bn, tid, acc);

    float mx = -3.4e38f;
    #pragma unroll
    for (int j = 0; j < 4; ++j) {
        const int col = bn + wc * 64 + j * 16 + l15;
        const float bb = bias[col];
        #pragma unroll
        for (int i = 0; i < 4; ++i) {
            const int row0 = bm + wr * 64 + i * 16 + quad * 4;
            #pragma unroll
            for (int r = 0; r < 4; ++r) {
                float v = acc[i][j][r] + bb;
                mx = fmaxf(mx, v);
                Cbf[(size_t)(row0 + r) * DM + col] = f2bf(v);
            }
        }
    }
    if (z == 1) {
        // wave covers one (b,h): rows bm..bm+127 (one b), cols bn+wc*64..+64.
        #pragma unroll
        for (int off = 32; off; off >>= 1) mx = fmaxf(mx, __shfl_xor(mx, off));
        if (lane == 0) {
            const int b = bm >> 12;
            const int h = (bn + wc * 64) >> 6;
            unsigned ub = __float_as_uint(mx);
            unsigned enc = (ub & 0x80000000u) ? ~ub : (ub | 0x80000000u);
            atomicMax(&kmOrd[b * NH + h], enc);
        }
    }
}

// ---------------------------------------------------------------------------
// final GEMM (128x256 tiles, 256 blocks): obf @ WoT + bo -> fp32 d_out
// ---------------------------------------------------------------------------
__global__ __launch_bounds__(512, 2) void gemm_out(
    const ushort_t* __restrict__ A, const ushort_t* __restrict__ BT,
    const float* __restrict__ bias, float* __restrict__ C)
{
    __shared__ ushort_t As[2 * ABUF];
    __shared__ ushort_t Bs[2 * BBUF];
    const int tid = threadIdx.x;
    int bm, bn;
    swz256(blockIdx.x, &bm, &bn);
    const int lane = tid & 63, w = tid >> 6;
    const int wr = w >> 2, wc = w & 3;
    const int quad = lane >> 4, l15 = lane & 15;

    f4_t acc[4][4] = {};
    gemm128_core(A, BT, As, Bs, bm, bn, tid, acc);

    #pragma unroll
    for (int j = 0; j < 4; ++j) {
        const int col = bn + wc * 64 + j * 16 + l15;
        const float bb = bias[col];
        #pragma unroll
        for (int i = 0; i < 4; ++i) {
            const int row0 = bm + wr * 64 + i * 16 + quad * 4;
            #pragma unroll
            for (int r = 0; r < 4; ++r)
                C[(size_t)(row0 + r) * DM + col] = acc[i][j][r] + bb;
        }
    }
}

// ---------------------------------------------------------------------------
// chunk_sums (MFMA) with INLINE FAVOR-K (favor_k kernel eliminated):
// loads RAW K rows, computes Kl = 1/8*exp(DN*K.Wfk - diag - mx) locally,
// writes Kt[m][t] transposed from the MFMA output, then the usual
// S^T[d][m] = sum_t V[t][d]*Kl[t][m]; row 64 = z[m]. bf16 out.
// (b,h) fixed per block -> the key max is ONE scalar from kmOrd.
// ---------------------------------------------------------------------------
__global__ __launch_bounds__(256) void chunk_sums_mfma(
    const ushort_t* __restrict__ Kbf, const ushort_t* __restrict__ Vbf,
    const float* __restrict__ Wfk, const unsigned* __restrict__ kmOrd,
    ushort_t* __restrict__ ST)
{
    const int bx = blockIdx.x;
    const int c = bx & 63, h = (bx >> 6) & 15, b = bx >> 10;
    __shared__ ushort_t Ks[64 * PITCH];   // raw K rows [t][m]
    __shared__ ushort_t Kt[64 * PITCH];   // favor'd K transposed [m][t]
    __shared__ ushort_t Vt[80 * PITCH];
    __shared__ ushort_t Ws[64 * PITCH];
    __shared__ float ssp[64][4];
    __shared__ float diag[64];
    const int tid = threadIdx.x;
    const int lane = tid & 63, w = tid >> 6;
    const int quad = lane >> 4, l15 = lane & 15;

    const size_t gbase = ((size_t)(b * SEQ + c * CT)) * DM + h * MD;

    // raw K rows (coalesced us8 copy) + V transposed
    #pragma unroll
    for (int r = 0; r < 2; ++r) {
        int idx = tid + r * 256;
        int row = idx >> 3, ch = idx & 7;
        *(us8_t*)&Ks[row * PITCH + ch * 8] =
            *(const us8_t*)&Kbf[gbase + (size_t)row * DM + ch * 8];
    }
    #pragma unroll
    for (int r = 0; r < 2; ++r) {
        int ch = w + r * 4;
        int t = lane;
        us8_t vv = *(const us8_t*)&Vbf[gbase + (size_t)t * DM + ch * 8];
        #pragma unroll
        for (int j = 0; j < 8; ++j) Vt[(ch * 8 + j) * PITCH + t] = vv[j];
    }
    if (tid < 64) Vt[64 * PITCH + tid] = (ushort_t)0x3F80;
    // Ws = DN * Wfk
    const float4* Wf4 = (const float4*)Wfk;
    #pragma unroll
    for (int i = 0; i < 4; ++i) {
        int f4i = tid + i * 256;
        int row = f4i >> 4, q4 = f4i & 15;
        float4 wv = Wf4[f4i];
        Ws[row * PITCH + q4 * 4 + 0] = f2bf(DN * wv.x);
        Ws[row * PITCH + q4 * 4 + 1] = f2bf(DN * wv.y);
        Ws[row * PITCH + q4 * 4 + 2] = f2bf(DN * wv.z);
        Ws[row * PITCH + q4 * 4 + 3] = f2bf(DN * wv.w);
    }
    __syncthreads();

    // diag[t] = ||K[t]||^2 * DIAG_SCALE
    {
        const int row = tid >> 2, seg = tid & 3;
        const us8_t* xp = (const us8_t*)&Ks[row * PITCH + seg * 16];
        us8_t a = xp[0], b2 = xp[1];
        float ss = 0.f;
        #pragma unroll
        for (int j = 0; j < 8; ++j) {
            float x0 = bf2f(a[j]), x1 = bf2f(b2[j]);
            ss += x0 * x0 + x1 * x1;
        }
        ssp[row][seg] = ss;
    }
    __syncthreads();
    if (tid < 64)
        diag[tid] = (ssp[tid][0] + ssp[tid][1] + ssp[tid][2] + ssp[tid][3]) * DIAG_SCALE;
    unsigned u = kmOrd[b * NH + h];
    unsigned bits = (u & 0x80000000u) ? (u & 0x7FFFFFFFu) : ~u;
    const float mxs = DN * __uint_as_float(bits);
    __syncthreads();

    // favor MFMA: rows of Ks x rows of Ws -> write transposed Kt[m][t]
    {
        bf8_t xf[2];
        #pragma unroll
        for (int ks = 0; ks < 2; ++ks)
            xf[ks] = *(const bf8_t*)&Ks[(w * 16 + l15) * PITCH + ks * 32 + quad * 8];
        f4_t facc[4] = {};
        #pragma unroll
        for (int dt = 0; dt < 4; ++dt)
            #pragma unroll
            for (int ks = 0; ks < 2; ++ks) {
                bf8_t wfr = *(const bf8_t*)&Ws[(dt * 16 + l15) * PITCH + ks * 32 + quad * 8];
                facc[dt] = __builtin_amdgcn_mfma_f32_16x16x32_bf16(xf[ks], wfr, facc[dt], 0, 0, 0);
            }
        #pragma unroll
        for (int r = 0; r < 4; ++r) {
            int t = w * 16 + quad * 4 + r;
            float d_ = diag[t];
            #pragma unroll
            for (int dt = 0; dt < 4; ++dt) {
                float e = facc[dt][r] - d_ - mxs + 1e-8f;
                Kt[(dt * 16 + l15) * PITCH + t] = f2bf(INV_SQRT_M * expf(e));
            }
        }
    }
    __syncthreads();

    ushort_t* Sg = ST + (size_t)((b * NH + h) * NCHUNK + c) * STSZ;

    bf8_t vf[2];
    #pragma unroll
    for (int ks = 0; ks < 2; ++ks)
        vf[ks] = *(const bf8_t*)&Vt[(w * 16 + l15) * PITCH + ks * 32 + quad * 8];
    f4_t acc[4] = {};
    #pragma unroll
    for (int mt = 0; mt < 4; ++mt)
        #pragma unroll
        for (int ks = 0; ks < 2; ++ks) {
            bf8_t kf = *(const bf8_t*)&Kt[(mt * 16 + l15) * PITCH + ks * 32 + quad * 8];
            acc[mt] = __builtin_amdgcn_mfma_f32_16x16x32_bf16(vf[ks], kf, acc[mt], 0, 0, 0);
        }
    #pragma unroll
    for (int mt = 0; mt < 4; ++mt)
        #pragma unroll
        for (int r = 0; r < 4; ++r)
            Sg[(w * 16 + quad * 4 + r) * 64 + mt * 16 + l15] = f2bf(acc[mt][r]);

    if (w == 0) {
        bf8_t vf4[2];
        #pragma unroll
        for (int ks = 0; ks < 2; ++ks)
            vf4[ks] = *(const bf8_t*)&Vt[(64 + l15) * PITCH + ks * 32 + quad * 8];
        f4_t accz[4] = {};
        #pragma unroll
        for (int mt = 0; mt < 4; ++mt)
            #pragma unroll
            for (int ks = 0; ks < 2; ++ks) {
                bf8_t kf = *(const bf8_t*)&Kt[(mt * 16 + l15) * PITCH + ks * 32 + quad * 8];
                accz[mt] = __builtin_amdgcn_mfma_f32_16x16x32_bf16(vf4[ks], kf, accz[mt], 0, 0, 0);
            }
        if (quad == 0) {
            #pragma unroll
            for (int mt = 0; mt < 4; ++mt)
                Sg[64 * 64 + mt * 16 + l15] = f2bf(accz[mt][0]);
        }
    }
}

// ---------------------------------------------------------------------------
// Exclusive prefix over chunks on bf16 ST; register-pipelined.
// ---------------------------------------------------------------------------
__global__ __launch_bounds__(256) void prefix_scan_st(ushort_t* __restrict__ ST)
{
    const int sb = blockIdx.x / 17;
    const int e = (blockIdx.x % 17) * 256 + threadIdx.x;
    if (e >= STSZ) return;
    ushort_t* p = ST + (size_t)sb * NCHUNK * STSZ + e;
    ushort_t v[NCHUNK];
    #pragma unroll
    for (int c = 0; c < NCHUNK; ++c) v[c] = p[(size_t)c * STSZ];
    float run = 0.f;
    #pragma unroll
    for (int c = 0; c < NCHUNK; ++c) {
        float cur = bf2f(v[c]);
        p[(size_t)c * STSZ] = f2bf(run);
        run += cur;
    }
}

// ---------------------------------------------------------------------------
// intra-chunk causal attention (MFMA) with inline FAVOR-q AND FAVOR-k
// (raw K in; favor'd in-place in LDS; favor_k kernel eliminated).
// ---------------------------------------------------------------------------
__global__ __launch_bounds__(256) void intra_attn_mfma(
    const ushort_t* __restrict__ Qraw, const ushort_t* __restrict__ Kbf,
    const ushort_t* __restrict__ Vbf, const ushort_t* __restrict__ ST,
    const float* __restrict__ Wfq, const float* __restrict__ Wfk,
    const unsigned* __restrict__ kmOrd, ushort_t* __restrict__ Obf)
{
    const int bx = blockIdx.x;
    const int c = bx & 63, h = (bx >> 6) & 15, b = bx >> 10;
    __shared__ ushort_t Qs[64 * PITCH];
    __shared__ ushort_t Ks[64 * PITCH];
    __shared__ ushort_t Vt[80 * PITCH];
    __shared__ ushort_t St[80 * PITCH];
    __shared__ ushort_t Ws[64 * PITCH];
    __shared__ float ssp[64][4];
    __shared__ float mxp[64][4];
    __shared__ float diag[64], mxr[64], dens[64];
    const int tid = threadIdx.x;
    const int lane = tid & 63, w = tid >> 6;
    const int quad = lane >> 4, l15 = lane & 15;

    const size_t gbase = ((size_t)(b * SEQ + c * CT)) * DM + h * MD;

    #pragma unroll
    for (int r = 0; r < 2; ++r) {
        int idx = tid + r * 256;
        int row = idx >> 3, ch = idx & 7;
        us8_t qv = *(const us8_t*)&Qraw[gbase + (size_t)row * DM + ch * 8];
        us8_t kv = *(const us8_t*)&Kbf[gbase + (size_t)row * DM + ch * 8];
        *(us8_t*)&Qs[row * PITCH + ch * 8] = qv;
        *(us8_t*)&Ks[row * PITCH + ch * 8] = kv;
    }
    #pragma unroll
    for (int r = 0; r < 2; ++r) {
        int ch = w + r * 4;
        int t = lane;
        us8_t vv = *(const us8_t*)&Vbf[gbase + (size_t)t * DM + ch * 8];
        #pragma unroll
        for (int j = 0; j < 8; ++j) Vt[(ch * 8 + j) * PITCH + t] = vv[j];
    }
    #pragma unroll
    for (int r = 0; r < 4; ++r) {
        int idx = tid + r * 256;
        int row = 64 + (idx >> 6), t = idx & 63;
        Vt[row * PITCH + t] = (row == 64) ? (ushort_t)0x3F80 : (ushort_t)0;
    }
    const us8_t* Sg8 = (const us8_t*)(ST + (size_t)((b * NH + h) * NCHUNK + c) * STSZ);
    #pragma unroll
    for (int r = 0; r < 3; ++r) {
        int idx = tid + r * 256;
        if (idx < 520) {
            int d = idx >> 3, mo = (idx & 7) * 8;
            *(us8_t*)&St[d * PITCH + mo] = Sg8[idx];
        }
        int idx2 = idx - 520;
        if (idx2 >= 0 && idx2 < 120) {
            int row = 65 + (idx2 >> 3), mo = (idx2 & 7) * 8;
            us8_t z = {};
            *(us8_t*)&St[row * PITCH + mo] = z;
        }
    }
    const float4* Wq4 = (const float4*)Wfq;
    #pragma unroll
    for (int i = 0; i < 4; ++i) {
        int f4i = tid + i * 256;
        int row = f4i >> 4, q4 = f4i & 15;
        float4 wv = Wq4[f4i];
        Ws[row * PITCH + q4 * 4 + 0] = f2bf(DN * wv.x);
        Ws[row * PITCH + q4 * 4 + 1] = f2bf(DN * wv.y);
        Ws[row * PITCH + q4 * 4 + 2] = f2bf(DN * wv.z);
        Ws[row * PITCH + q4 * 4 + 3] = f2bf(DN * wv.w);
    }
    __syncthreads();

    // ---- FAVOR-q: per-row diag + per-row max ----
    {
        const int row = tid >> 2, seg = tid & 3;
        const us8_t* xp = (const us8_t*)&Qs[row * PITCH + seg * 16];
        us8_t a = xp[0], b2 = xp[1];
        float ss = 0.f, mx = -3.4e38f;
        #pragma unroll
        for (int j = 0; j < 8; ++j) {
            float x0 = bf2f(a[j]), x1 = bf2f(b2[j]);
            ss += x0 * x0 + x1 * x1;
            mx = fmaxf(mx, fmaxf(x0, x1));
        }
        ssp[row][seg] = ss;
        mxp[row][seg] = mx;
    }
    __syncthreads();
    if (tid < 64) {
        diag[tid] = (ssp[tid][0] + ssp[tid][1] + ssp[tid][2] + ssp[tid][3]) * DIAG_SCALE;
        mxr[tid] = DN * fmaxf(fmaxf(mxp[tid][0], mxp[tid][1]),
                              fmaxf(mxp[tid][2], mxp[tid][3]));
    }
    __syncthreads();

    {
        bf8_t xf[2];
        #pragma unroll
        for (int ks = 0; ks < 2; ++ks)
            xf[ks] = *(const bf8_t*)&Qs[(w * 16 + l15) * PITCH + ks * 32 + quad * 8];
        f4_t facc[4] = {};
        #pragma unroll
        for (int dt = 0; dt < 4; ++dt)
            #pragma unroll
            for (int ks = 0; ks < 2; ++ks) {
                bf8_t wfr = *(const bf8_t*)&Ws[(dt * 16 + l15) * PITCH + ks * 32 + quad * 8];
                facc[dt] = __builtin_amdgcn_mfma_f32_16x16x32_bf16(xf[ks], wfr, facc[dt], 0, 0, 0);
            }
        __syncthreads();
        #pragma unroll
        for (int r = 0; r < 4; ++r) {
            int row = w * 16 + quad * 4 + r;
            float d_ = diag[row], m_ = mxr[row];
            #pragma unroll
            for (int dt = 0; dt < 4; ++dt) {
                float e = facc[dt][r] - d_ - m_ + 1e-8f;
                Qs[row * PITCH + dt * 16 + l15] = f2bf(INV_SQRT_M * expf(e));
            }
        }
    }
    __syncthreads();

    // ---- FAVOR-k: reload Ws with DN*Wfk (Ws free after barrier above);
    //      diag over raw Ks rows (reuse ssp/diag); global (b,h) max scalar ----
    const float4* Wk4 = (const float4*)Wfk;
    #pragma unroll
    for (int i = 0; i < 4; ++i) {
        int f4i = tid + i * 256;
        int row = f4i >> 4, q4 = f4i & 15;
        float4 wv = Wk4[f4i];
        Ws[row * PITCH + q4 * 4 + 0] = f2bf(DN * wv.x);
        Ws[row * PITCH + q4 * 4 + 1] = f2bf(DN * wv.y);
        Ws[row * PITCH + q4 * 4 + 2] = f2bf(DN * wv.z);
        Ws[row * PITCH + q4 * 4 + 3] = f2bf(DN * wv.w);
    }
    {
        const int row = tid >> 2, seg = tid & 3;
        const us8_t* xp = (const us8_t*)&Ks[row * PITCH + seg * 16];
        us8_t a = xp[0], b2 = xp[1];
        float ss = 0.f;
        #pragma unroll
        for (int j = 0; j < 8; ++j) {
            float x0 = bf2f(a[j]), x1 = bf2f(b2[j]);
            ss += x0 * x0 + x1 * x1;
        }
        ssp[row][seg] = ss;
    }
    __syncthreads();
    if (tid < 64)
        diag[tid] = (ssp[tid][0] + ssp[tid][1] + ssp[tid][2] + ssp[tid][3]) * DIAG_SCALE;
    unsigned ku = kmOrd[b * NH + h];
    unsigned kbits = (ku & 0x80000000u) ? (ku & 0x7FFFFFFFu) : ~ku;
    const float mxs = DN * __uint_as_float(kbits);
    __syncthreads();

    {
        bf8_t xf[2];
        #pragma unroll
        for (int ks = 0; ks < 2; ++ks)
            xf[ks] = *(const bf8_t*)&Ks[(w * 16 + l15) * PITCH + ks * 32 + quad * 8];
        f4_t facc[4] = {};
        #pragma unroll
        for (int dt = 0; dt < 4; ++dt)
            #pragma unroll
            for (int ks = 0; ks < 2; ++ks) {
                bf8_t wfr = *(const bf8_t*)&Ws[(dt * 16 + l15) * PITCH + ks * 32 + quad * 8];
                facc[dt] = __builtin_amdgcn_mfma_f32_16x16x32_bf16(xf[ks], wfr, facc[dt], 0, 0, 0);
            }
        __syncthreads();          // all raw-Ks reads done before in-place write
        #pragma unroll
        for (int r = 0; r < 4; ++r) {
            int row = w * 16 + quad * 4 + r;
            float d_ = diag[row];
            #pragma unroll
            for (int dt = 0; dt < 4; ++dt) {
                float e = facc[dt][r] - d_ - mxs + 1e-8f;
                Ks[row * PITCH + dt * 16 + l15] = f2bf(INV_SQRT_M * expf(e));
            }
        }
    }
    __syncthreads();

    // ---- QK^T (both favor'd) ----
    bf8_t qf[2];
    #pragma unroll
    for (int ks = 0; ks < 2; ++ks)
        qf[ks] = *(const bf8_t*)&Qs[(w * 16 + l15) * PITCH + ks * 32 + quad * 8];
    f4_t accA[4] = {};
    #pragma unroll
    for (int jt = 0; jt < 4; ++jt)
        #pragma unroll
        for (int ks = 0; ks < 2; ++ks) {
            bf8_t kf = *(const bf8_t*)&Ks[(jt * 16 + l15) * PITCH + ks * 32 + quad * 8];
            accA[jt] = __builtin_amdgcn_mfma_f32_16x16x32_bf16(qf[ks], kf, accA[jt], 0, 0, 0);
        }
    __syncthreads();
    #pragma unroll
    for (int jt = 0; jt < 4; ++jt) {
        int j = jt * 16 + l15;
        #pragma unroll
        for (int r = 0; r < 4; ++r) {
            int i = w * 16 + quad * 4 + r;
            float a = (j <= i) ? accA[jt][r] : 0.f;
            Ks[i * PITCH + j] = f2bf(a);
        }
    }
    __syncthreads();

    bf8_t af[2];
    #pragma unroll
    for (int ks = 0; ks < 2; ++ks)
        af[ks] = *(const bf8_t*)&Ks[(w * 16 + l15) * PITCH + ks * 32 + quad * 8];
    f4_t acc[5] = {};
    #pragma unroll
    for (int dt = 0; dt < 5; ++dt)
        #pragma unroll
        for (int ks = 0; ks < 2; ++ks) {
            bf8_t sf = *(const bf8_t*)&St[(dt * 16 + l15) * PITCH + ks * 32 + quad * 8];
            acc[dt] = __builtin_amdgcn_mfma_f32_16x16x32_bf16(qf[ks], sf, acc[dt], 0, 0, 0);
            bf8_t vf = *(const bf8_t*)&Vt[(dt * 16 + l15) * PITCH + ks * 32 + quad * 8];
            acc[dt] = __builtin_amdgcn_mfma_f32_16x16x32_bf16(af[ks], vf, acc[dt], 0, 0, 0);
        }
    if (l15 == 0) {
        #pragma unroll
        for (int r = 0; r < 4; ++r) dens[w * 16 + quad * 4 + r] = acc[4][r];
    }
    __syncthreads();

    #pragma unroll
    for (int r = 0; r < 4; ++r) {
        int i = w * 16 + quad * 4 + r;
        float inv = 1.0f / dens[i];
        #pragma unroll
        for (int dt = 0; dt < 4; ++dt)
            Obf[gbase + (size_t)i * DM + dt * 16 + l15] = f2bf(acc[dt][r] * inv);
    }
}

// ---------------------------------------------------------------------------
extern "C" void kernel_launch(void* const* d_in, const int* in_sizes, int n_in,
                              void* d_out, int out_size, void* d_ws, size_t ws_size,
                              hipStream_t stream)
{
    const float* queries = (const float*)d_in[0];
    const float* keys    = (const float*)d_in[1];
    const float* values  = (const float*)d_in[2];
    const float* Wq = (const float*)d_in[3];  const float* bq = (const float*)d_in[4];
    const float* Wk = (const float*)d_in[5];  const float* bk = (const float*)d_in[6];
    const float* Wv = (const float*)d_in[7];  const float* bv = (const float*)d_in[8];
    const float* Wo = (const float*)d_in[9];  const float* bo = (const float*)d_in[10];
    const float* Wfq = (const float*)d_in[11];
    const float* Wfk = (const float*)d_in[12];

    char* ws = (char*)d_ws;
    unsigned* kmOrd = (unsigned*)ws;                       // [32] (pad)
    ushort_t* STb = (ushort_t*)(ws + 256);                 // [32,64,65*64] bf16
    ushort_t* qbf = STb + (size_t)32 * NCHUNK * STSZ;      // qkv bf16 GEMM outputs
    ushort_t* kbf = qbf + (size_t)NROW * DM;
    ushort_t* vbf = kbf + (size_t)NROW * DM;
    ushort_t* obf = vbf + (size_t)NROW * DM;               // bf16 attn out
    ushort_t* xcvt = obf + (size_t)NROW * DM;              // 3x bf16 converted inputs
    ushort_t* wT  = xcvt + (size_t)3 * NROW * DM;          // 4 x [1024,1024] bf16
    ushort_t* WoT = wT + (size_t)3 * DM * DM;

    prep_weights<<<dim3(32, 32, 4), 256, 0, stream>>>(Wq, Wk, Wv, Wo, wT, kmOrd);

    const int n8 = NROW * DM / 8;
    cvt_qkv<<<dim3(n8 / 256, 3), 256, 0, stream>>>(queries, keys, values, xcvt);

    gemm_qkv<<<dim3(256, 3), 512, 0, stream>>>(xcvt, wT, bq, bk, bv, qbf, kmOrd);

    chunk_sums_mfma<<<BATCH * NH * NCHUNK, 256, 0, stream>>>(kbf, vbf, Wfk, kmOrd, STb);
    prefix_scan_st<<<32 * 17, 256, 0, stream>>>(STb);
    intra_attn_mfma<<<BATCH * NH * NCHUNK, 256, 0, stream>>>(qbf, kbf, vbf, STb,
                                                             Wfq, Wfk, kmOrd, obf);

    gemm_out<<<256, 512, 0, stream>>>(obf, WoT, bo, (float*)d_out);
}

// Round 8
// 310.733 us; speedup vs baseline: 1.1027x; 1.0084x over previous
//
#include <hip/hip_runtime.h>
#include <math.h>

// Problem constants: B=2, L=4096, d_model=1024, H=16, M=D=64
#define BATCH 2
#define SEQ   4096
#define DM    1024
#define NH    16
#define MD    64
#define NROW  (BATCH*SEQ)     // 8192
#define RQ    (BATCH*SEQ*NH)  // 131072
#define NCHUNK 64
#define CT     64
#define DN    0.35355339059327373f
#define INV_SQRT_M 0.125f
#define PITCH 72              // ushort row pitch for bf16 LDS tiles
#define STSZ  (65*64)         // per-(bh,c) S^T chunk: rows d=0..64 (row 64 = z)
#define DIAG_SCALE (0.125f * 0.0625f)   // DN^2 * 0.5*DN^2

typedef unsigned short ushort_t;
typedef short bf8_t __attribute__((ext_vector_type(8)));
typedef float f4_t  __attribute__((ext_vector_type(4)));
typedef ushort_t us8_t __attribute__((ext_vector_type(8)));

__device__ static inline ushort_t f2bf(float f) {
    union { float f; unsigned u; } v; v.f = f;
    unsigned r = v.u + 0x7FFFu + ((v.u >> 16) & 1u);   // RNE
    return (ushort_t)(r >> 16);
}
__device__ static inline float bf2f(ushort_t u) {
    union { unsigned u; float f; } v; v.u = ((unsigned)u) << 16;
    return v.f;
}

__device__ static inline void async_ld16(const ushort_t* g, ushort_t* l) {
    __builtin_amdgcn_global_load_lds(
        (const __attribute__((address_space(1))) unsigned int*)g,
        (__attribute__((address_space(3))) unsigned int*)l,
        16, 0, 0);
}

__device__ static inline void sbar() {
    __builtin_amdgcn_sched_barrier(0);
    __builtin_amdgcn_s_barrier();
    __builtin_amdgcn_sched_barrier(0);
}
#define VMCNT(n) do { asm volatile("s_waitcnt vmcnt(" #n ")" ::: "memory"); \
                      __builtin_amdgcn_sched_barrier(0); } while (0)

#define TBUF (128*64)   // ushorts per tile buffer (16 KiB)

// ---------------------------------------------------------------------------
// 128x128-tile bf16 GEMM core, 256 threads = 4 waves (2M x 2N), per-wave
// output 64x64 (acc[4][4]), BK=64, K=1024.  LDS: A[2]+B[2] x 16 KiB = 64 KiB
// -> 2 blocks/CU (the point: two independent barrier groups per CU so one
// block's MFMA covers the other's stage/barrier stalls — m114 overlap).
// Schedule (minimum 2-phase T3, counted wait, never drains in-loop):
//   prologue: stage A(0),B(0)->buf0 [8 loads/thread... 8 wave-instr total]
//   iter t:   issue A,B(t+1)->s^1 [8]; VMCNT(8) (publishes A,B(t)); sbar;
//             rd(s,ks0); 16 MFMA; rd(s,ks1); 16 MFMA; sbar
//   tile 15:  VMCNT(0); sbar; rd; mm x2
// Ledger: VMCNT(8) leaves exactly the 8 newest (tile t+1) outstanding ->
// tile t published before first read; issue-to-use = 1 iteration (>= HBM
// latency). Overwrite of s^1 fenced by iter t-1's closing barrier.
// T2 swizzle: LDS dest linear (global_load_lds); global SOURCE col pre-XOR'd
// (kcol=((l&7)^(l>>3))*8); read slot XOR'd with row&7. Conflict-free b128
// (HW-verified: SQ_LDS_BANK_CONFLICT = 0).
// ---------------------------------------------------------------------------
__device__ static inline void gemm_tile_core(
    const ushort_t* __restrict__ A, const ushort_t* __restrict__ BT,
    ushort_t* As, ushort_t* Bs, int bm, int bn, int tid, f4_t acc[4][4])
{
    const int lane = tid & 63, w = tid >> 6;        // 4 waves
    const int wr = w >> 1, wc = w & 1;              // 2 x 2 wave grid
    const int quad = lane >> 4, l15 = lane & 15;
    const int lrow = lane >> 3;                     // 0..7
    const int kcol = ((lane & 7) ^ lrow) * 8;       // inverse-swizzled src col

    auto stA = [&](int t, int s) {                  // 4 loads/thread
        #pragma unroll
        for (int c = 0; c < 4; ++c) {
            const int r0 = c * 32 + w * 8;
            async_ld16(A + (size_t)(bm + r0 + lrow) * DM + t * 64 + kcol,
                       &As[s * TBUF + r0 * 64]);
        }
    };
    auto stB = [&](int t, int s) {
        #pragma unroll
        for (int c = 0; c < 4; ++c) {
            const int r0 = c * 32 + w * 8;
            async_ld16(BT + (size_t)(bn + r0 + lrow) * DM + t * 64 + kcol,
                       &Bs[s * TBUF + r0 * 64]);
        }
    };

    bf8_t af[4], bf[4];
    auto rdFrags = [&](int s, int ks) {
        const int slot8 = (((ks << 2) | quad) ^ (l15 & 7)) * 8;
        #pragma unroll
        for (int i = 0; i < 4; ++i)
            af[i] = *(const bf8_t*)&As[s * TBUF + (wr * 64 + i * 16 + l15) * 64 + slot8];
        #pragma unroll
        for (int j = 0; j < 4; ++j)
            bf[j] = *(const bf8_t*)&Bs[s * TBUF + (wc * 64 + j * 16 + l15) * 64 + slot8];
    };
    auto mm = [&]() {
        __builtin_amdgcn_s_setprio(1);
        #pragma unroll
        for (int i = 0; i < 4; ++i)
            #pragma unroll
            for (int j = 0; j < 4; ++j)
                acc[i][j] = __builtin_amdgcn_mfma_f32_16x16x32_bf16(
                    af[i], bf[j], acc[i][j], 0, 0, 0);
        __builtin_amdgcn_s_setprio(0);
    };

    // prologue: tile 0 -> buf 0 (8 loads); no drain needed (loop's VMCNT(8)
    // at t=0 publishes them).
    stA(0, 0); stB(0, 0);

    #pragma unroll 1
    for (int t = 0; t < 15; ++t) {
        const int s = t & 1;
        stA(t + 1, s ^ 1); stB(t + 1, s ^ 1);   // 8 newest
        VMCNT(8);                               // publishes A,B(t) -> buf s
        sbar();
        rdFrags(s, 0);
        mm();
        rdFrags(s, 1);
        mm();
        sbar();                                 // all reads of buf s done
    }
    // tile 15 (buf 1): drain its 8 loads, no further stages.
    VMCNT(0);
    sbar();
    rdFrags(1, 0);
    mm();
    rdFrags(1, 1);
    mm();
}

// XCD-aware bijective remap of 512 blocks (64 bm x 8 bn panels of 128x128).
// xcd = bx%8 gets bm panels [xcd*8, xcd*8+8) x all 8 bn (bn fastest):
// B (2 MB weights) L2-resident, A panel reused 8x per XCD.
__device__ static inline void swz512(int bx, int* bm, int* bn) {
    const int xcd = bx & 7, s = bx >> 3;        // s: 0..63
    *bm = (xcd * 8 + (s >> 3)) << 7;
    *bn = (s & 7) << 7;
}

// ---------------------------------------------------------------------------
// prep: 4x transpose_cvt (z selects weight) + zero kmOrd.
// ---------------------------------------------------------------------------
__global__ __launch_bounds__(256) void prep_weights(
    const float* __restrict__ W0, const float* __restrict__ W1,
    const float* __restrict__ W2, const float* __restrict__ W3,
    ushort_t* __restrict__ WT, unsigned* __restrict__ kmOrd)
{
    if (blockIdx.z == 0 && blockIdx.x == 0 && blockIdx.y == 0 && threadIdx.x < 32)
        kmOrd[threadIdx.x] = 0u;
    const float* W = blockIdx.z == 0 ? W0 : (blockIdx.z == 1 ? W1 : (blockIdx.z == 2 ? W2 : W3));
    ushort_t* dst = WT + (size_t)blockIdx.z * DM * DM;
    __shared__ float t[32][33];
    const int k0 = blockIdx.x * 32, n0 = blockIdx.y * 32;
    const int tx = threadIdx.x & 31, ty = threadIdx.x >> 5;
    #pragma unroll
    for (int r = 0; r < 32; r += 8)
        t[ty + r][tx] = W[(size_t)(k0 + ty + r) * 1024 + n0 + tx];
    __syncthreads();
    #pragma unroll
    for (int r = 0; r < 32; r += 8)
        dst[(size_t)(n0 + ty + r) * 1024 + k0 + tx] = f2bf(t[tx][ty + r]);
}

// ---------------------------------------------------------------------------
// fused fp32 -> bf16 convert for q,k,v
// ---------------------------------------------------------------------------
__global__ __launch_bounds__(256) void cvt_qkv(
    const float* __restrict__ Q, const float* __restrict__ K,
    const float* __restrict__ V, ushort_t* __restrict__ Y)
{
    const int y = blockIdx.y;
    const float* X = y == 0 ? Q : (y == 1 ? K : V);
    ushort_t* dst = Y + (size_t)y * NROW * DM;
    int i = blockIdx.x * 256 + threadIdx.x;
    const float4* X4 = (const float4*)X;
    float4 a = X4[i * 2], b = X4[i * 2 + 1];
    us8_t o;
    o[0]=f2bf(a.x); o[1]=f2bf(a.y); o[2]=f2bf(a.z); o[3]=f2bf(a.w);
    o[4]=f2bf(b.x); o[5]=f2bf(b.y); o[6]=f2bf(b.z); o[7]=f2bf(b.w);
    *(us8_t*)&dst[i * 8] = o;
}

// ---------------------------------------------------------------------------
// merged QKV GEMM (128x128 tiles, 2 blocks/CU): blockIdx.y selects z slice.
// z==1 (keys) folds per-(b,h) output max into kmOrd via ordered-uint atomicMax.
// ---------------------------------------------------------------------------
__global__ __launch_bounds__(256, 2) void gemm_qkv(
    const ushort_t* __restrict__ Xc, const ushort_t* __restrict__ WT,
    const float* __restrict__ bq, const float* __restrict__ bk,
    const float* __restrict__ bv, ushort_t* __restrict__ Obase,
    unsigned* __restrict__ kmOrd)
{
    __shared__ ushort_t As[2 * TBUF];
    __shared__ ushort_t Bs[2 * TBUF];
    const int z = blockIdx.y;
    const ushort_t* A  = Xc + (size_t)z * NROW * DM;
    const ushort_t* BT = WT + (size_t)z * DM * DM;
    const float* bias = z == 0 ? bq : (z == 1 ? bk : bv);
    ushort_t* Cbf = Obase + (size_t)z * NROW * DM;

    const int tid = threadIdx.x;
    int bm, bn;
    swz512(blockIdx.x, &bm, &bn);
    const int lane = tid & 63, w = tid >> 6;
    const int wr = w >> 1, wc = w & 1;
    const int quad = lane >> 4, l15 = lane & 15;

    f4_t acc[4][4] = {};
    gemm_tile_core(A, BT, As, Bs, bm, bn, tid, acc);

    float mx = -3.4e38f;
    #pragma unroll
    for (int j = 0; j < 4; ++j) {
        const int col = bn + wc * 64 + j * 16 + l15;
        const float bb = bias[col];
        #pragma unroll
        for (int i = 0; i < 4; ++i) {
            const int row0 = bm + wr * 64 + i * 16 + quad * 4;
            #pragma unroll
            for (int r = 0; r < 4; ++r) {
                float v = acc[i][j][r] + bb;
                mx = fmaxf(mx, v);
                Cbf[(size_t)(row0 + r) * DM + col] = f2bf(v);
            }
        }
    }
    if (z == 1) {
        // wave covers one (b,h): rows bm+wr*64..+64 (one b), cols bn+wc*64..+64.
        #pragma unroll
        for (int off = 32; off; off >>= 1) mx = fmaxf(mx, __shfl_xor(mx, off));
        if (lane == 0) {
            const int b = bm >> 12;
            const int h = (bn + wc * 64) >> 6;
            unsigned ub = __float_as_uint(mx);
            unsigned enc = (ub & 0x80000000u) ? ~ub : (ub | 0x80000000u);
            atomicMax(&kmOrd[b * NH + h], enc);
        }
    }
}

// ---------------------------------------------------------------------------
// final GEMM (128x128 tiles, 512 blocks, 2 blocks/CU): obf @ WoT + bo -> fp32
// ---------------------------------------------------------------------------
__global__ __launch_bounds__(256, 2) void gemm_out(
    const ushort_t* __restrict__ A, const ushort_t* __restrict__ BT,
    const float* __restrict__ bias, float* __restrict__ C)
{
    __shared__ ushort_t As[2 * TBUF];
    __shared__ ushort_t Bs[2 * TBUF];
    const int tid = threadIdx.x;
    int bm, bn;
    swz512(blockIdx.x, &bm, &bn);
    const int lane = tid & 63, w = tid >> 6;
    const int wr = w >> 1, wc = w & 1;
    const int quad = lane >> 4, l15 = lane & 15;

    f4_t acc[4][4] = {};
    gemm_tile_core(A, BT, As, Bs, bm, bn, tid, acc);

    #pragma unroll
    for (int j = 0; j < 4; ++j) {
        const int col = bn + wc * 64 + j * 16 + l15;
        const float bb = bias[col];
        #pragma unroll
        for (int i = 0; i < 4; ++i) {
            const int row0 = bm + wr * 64 + i * 16 + quad * 4;
            #pragma unroll
            for (int r = 0; r < 4; ++r)
                C[(size_t)(row0 + r) * DM + col] = acc[i][j][r] + bb;
        }
    }
}

// ---------------------------------------------------------------------------
// chunk_sums (MFMA) with INLINE FAVOR-K:
// loads RAW K rows, computes Kl = 1/8*exp(DN*K.Wfk - diag - mx) locally,
// writes Kt[m][t] transposed from the MFMA output, then
// S^T[d][m] = sum_t V[t][d]*Kl[t][m]; row 64 = z[m]. bf16 out.
// ---------------------------------------------------------------------------
__global__ __launch_bounds__(256) void chunk_sums_mfma(
    const ushort_t* __restrict__ Kbf, const ushort_t* __restrict__ Vbf,
    const float* __restrict__ Wfk, const unsigned* __restrict__ kmOrd,
    ushort_t* __restrict__ ST)
{
    const int bx = blockIdx.x;
    const int c = bx & 63, h = (bx >> 6) & 15, b = bx >> 10;
    __shared__ ushort_t Ks[64 * PITCH];   // raw K rows [t][m]
    __shared__ ushort_t Kt[64 * PITCH];   // favor'd K transposed [m][t]
    __shared__ ushort_t Vt[80 * PITCH];
    __shared__ ushort_t Ws[64 * PITCH];
    __shared__ float ssp[64][4];
    __shared__ float diag[64];
    const int tid = threadIdx.x;
    const int lane = tid & 63, w = tid >> 6;
    const int quad = lane >> 4, l15 = lane & 15;

    const size_t gbase = ((size_t)(b * SEQ + c * CT)) * DM + h * MD;

    #pragma unroll
    for (int r = 0; r < 2; ++r) {
        int idx = tid + r * 256;
        int row = idx >> 3, ch = idx & 7;
        *(us8_t*)&Ks[row * PITCH + ch * 8] =
            *(const us8_t*)&Kbf[gbase + (size_t)row * DM + ch * 8];
    }
    #pragma unroll
    for (int r = 0; r < 2; ++r) {
        int ch = w + r * 4;
        int t = lane;
        us8_t vv = *(const us8_t*)&Vbf[gbase + (size_t)t * DM + ch * 8];
        #pragma unroll
        for (int j = 0; j < 8; ++j) Vt[(ch * 8 + j) * PITCH + t] = vv[j];
    }
    if (tid < 64) Vt[64 * PITCH + tid] = (ushort_t)0x3F80;
    const float4* Wf4 = (const float4*)Wfk;
    #pragma unroll
    for (int i = 0; i < 4; ++i) {
        int f4i = tid + i * 256;
        int row = f4i >> 4, q4 = f4i & 15;
        float4 wv = Wf4[f4i];
        Ws[row * PITCH + q4 * 4 + 0] = f2bf(DN * wv.x);
        Ws[row * PITCH + q4 * 4 + 1] = f2bf(DN * wv.y);
        Ws[row * PITCH + q4 * 4 + 2] = f2bf(DN * wv.z);
        Ws[row * PITCH + q4 * 4 + 3] = f2bf(DN * wv.w);
    }
    __syncthreads();

    {
        const int row = tid >> 2, seg = tid & 3;
        const us8_t* xp = (const us8_t*)&Ks[row * PITCH + seg * 16];
        us8_t a = xp[0], b2 = xp[1];
        float ss = 0.f;
        #pragma unroll
        for (int j = 0; j < 8; ++j) {
            float x0 = bf2f(a[j]), x1 = bf2f(b2[j]);
            ss += x0 * x0 + x1 * x1;
        }
        ssp[row][seg] = ss;
    }
    __syncthreads();
    if (tid < 64)
        diag[tid] = (ssp[tid][0] + ssp[tid][1] + ssp[tid][2] + ssp[tid][3]) * DIAG_SCALE;
    unsigned u = kmOrd[b * NH + h];
    unsigned bits = (u & 0x80000000u) ? (u & 0x7FFFFFFFu) : ~u;
    const float mxs = DN * __uint_as_float(bits);
    __syncthreads();

    {
        bf8_t xf[2];
        #pragma unroll
        for (int ks = 0; ks < 2; ++ks)
            xf[ks] = *(const bf8_t*)&Ks[(w * 16 + l15) * PITCH + ks * 32 + quad * 8];
        f4_t facc[4] = {};
        #pragma unroll
        for (int dt = 0; dt < 4; ++dt)
            #pragma unroll
            for (int ks = 0; ks < 2; ++ks) {
                bf8_t wfr = *(const bf8_t*)&Ws[(dt * 16 + l15) * PITCH + ks * 32 + quad * 8];
                facc[dt] = __builtin_amdgcn_mfma_f32_16x16x32_bf16(xf[ks], wfr, facc[dt], 0, 0, 0);
            }
        #pragma unroll
        for (int r = 0; r < 4; ++r) {
            int t = w * 16 + quad * 4 + r;
            float d_ = diag[t];
            #pragma unroll
            for (int dt = 0; dt < 4; ++dt) {
                float e = facc[dt][r] - d_ - mxs + 1e-8f;
                Kt[(dt * 16 + l15) * PITCH + t] = f2bf(INV_SQRT_M * expf(e));
            }
        }
    }
    __syncthreads();

    ushort_t* Sg = ST + (size_t)((b * NH + h) * NCHUNK + c) * STSZ;

    bf8_t vf[2];
    #pragma unroll
    for (int ks = 0; ks < 2; ++ks)
        vf[ks] = *(const bf8_t*)&Vt[(w * 16 + l15) * PITCH + ks * 32 + quad * 8];
    f4_t acc[4] = {};
    #pragma unroll
    for (int mt = 0; mt < 4; ++mt)
        #pragma unroll
        for (int ks = 0; ks < 2; ++ks) {
            bf8_t kf = *(const bf8_t*)&Kt[(mt * 16 + l15) * PITCH + ks * 32 + quad * 8];
            acc[mt] = __builtin_amdgcn_mfma_f32_16x16x32_bf16(vf[ks], kf, acc[mt], 0, 0, 0);
        }
    #pragma unroll
    for (int mt = 0; mt < 4; ++mt)
        #pragma unroll
        for (int r = 0; r < 4; ++r)
            Sg[(w * 16 + quad * 4 + r) * 64 + mt * 16 + l15] = f2bf(acc[mt][r]);

    if (w == 0) {
        bf8_t vf4[2];
        #pragma unroll
        for (int ks = 0; ks < 2; ++ks)
            vf4[ks] = *(const bf8_t*)&Vt[(64 + l15) * PITCH + ks * 32 + quad * 8];
        f4_t accz[4] = {};
        #pragma unroll
        for (int mt = 0; mt < 4; ++mt)
            #pragma unroll
            for (int ks = 0; ks < 2; ++ks) {
                bf8_t kf = *(const bf8_t*)&Kt[(mt * 16 + l15) * PITCH + ks * 32 + quad * 8];
                accz[mt] = __builtin_amdgcn_mfma_f32_16x16x32_bf16(vf4[ks], kf, accz[mt], 0, 0, 0);
            }
        if (quad == 0) {
            #pragma unroll
            for (int mt = 0; mt < 4; ++mt)
                Sg[64 * 64 + mt * 16 + l15] = f2bf(accz[mt][0]);
        }
    }
}

// ---------------------------------------------------------------------------
// Exclusive prefix over chunks on bf16 ST; register-pipelined.
// ---------------------------------------------------------------------------
__global__ __launch_bounds__(256) void prefix_scan_st(ushort_t* __restrict__ ST)
{
    const int sb = blockIdx.x / 17;
    const int e = (blockIdx.x % 17) * 256 + threadIdx.x;
    if (e >= STSZ) return;
    ushort_t* p = ST + (size_t)sb * NCHUNK * STSZ + e;
    ushort_t v[NCHUNK];
    #pragma unroll
    for (int c = 0; c < NCHUNK; ++c) v[c] = p[(size_t)c * STSZ];
    float run = 0.f;
    #pragma unroll
    for (int c = 0; c < NCHUNK; ++c) {
        float cur = bf2f(v[c]);
        p[(size_t)c * STSZ] = f2bf(run);
        run += cur;
    }
}

// ---------------------------------------------------------------------------
// intra-chunk causal attention (MFMA) with inline FAVOR-q AND FAVOR-k.
// ---------------------------------------------------------------------------
__global__ __launch_bounds__(256) void intra_attn_mfma(
    const ushort_t* __restrict__ Qraw, const ushort_t* __restrict__ Kbf,
    const ushort_t* __restrict__ Vbf, const ushort_t* __restrict__ ST,
    const float* __restrict__ Wfq, const float* __restrict__ Wfk,
    const unsigned* __restrict__ kmOrd, ushort_t* __restrict__ Obf)
{
    const int bx = blockIdx.x;
    const int c = bx & 63, h = (bx >> 6) & 15, b = bx >> 10;
    __shared__ ushort_t Qs[64 * PITCH];
    __shared__ ushort_t Ks[64 * PITCH];
    __shared__ ushort_t Vt[80 * PITCH];
    __shared__ ushort_t St[80 * PITCH];
    __shared__ ushort_t Ws[64 * PITCH];
    __shared__ float ssp[64][4];
    __shared__ float mxp[64][4];
    __shared__ float diag[64], mxr[64], dens[64];
    const int tid = threadIdx.x;
    const int lane = tid & 63, w = tid >> 6;
    const int quad = lane >> 4, l15 = lane & 15;

    const size_t gbase = ((size_t)(b * SEQ + c * CT)) * DM + h * MD;

    #pragma unroll
    for (int r = 0; r < 2; ++r) {
        int idx = tid + r * 256;
        int row = idx >> 3, ch = idx & 7;
        us8_t qv = *(const us8_t*)&Qraw[gbase + (size_t)row * DM + ch * 8];
        us8_t kv = *(const us8_t*)&Kbf[gbase + (size_t)row * DM + ch * 8];
        *(us8_t*)&Qs[row * PITCH + ch * 8] = qv;
        *(us8_t*)&Ks[row * PITCH + ch * 8] = kv;
    }
    #pragma unroll
    for (int r = 0; r < 2; ++r) {
        int ch = w + r * 4;
        int t = lane;
        us8_t vv = *(const us8_t*)&Vbf[gbase + (size_t)t * DM + ch * 8];
        #pragma unroll
        for (int j = 0; j < 8; ++j) Vt[(ch * 8 + j) * PITCH + t] = vv[j];
    }
    #pragma unroll
    for (int r = 0; r < 4; ++r) {
        int idx = tid + r * 256;
        int row = 64 + (idx >> 6), t = idx & 63;
        Vt[row * PITCH + t] = (row == 64) ? (ushort_t)0x3F80 : (ushort_t)0;
    }
    const us8_t* Sg8 = (const us8_t*)(ST + (size_t)((b * NH + h) * NCHUNK + c) * STSZ);
    #pragma unroll
    for (int r = 0; r < 3; ++r) {
        int idx = tid + r * 256;
        if (idx < 520) {
            int d = idx >> 3, mo = (idx & 7) * 8;
            *(us8_t*)&St[d * PITCH + mo] = Sg8[idx];
        }
        int idx2 = idx - 520;
        if (idx2 >= 0 && idx2 < 120) {
            int row = 65 + (idx2 >> 3), mo = (idx2 & 7) * 8;
            us8_t z = {};
            *(us8_t*)&St[row * PITCH + mo] = z;
        }
    }
    const float4* Wq4 = (const float4*)Wfq;
    #pragma unroll
    for (int i = 0; i < 4; ++i) {
        int f4i = tid + i * 256;
        int row = f4i >> 4, q4 = f4i & 15;
        float4 wv = Wq4[f4i];
        Ws[row * PITCH + q4 * 4 + 0] = f2bf(DN * wv.x);
        Ws[row * PITCH + q4 * 4 + 1] = f2bf(DN * wv.y);
        Ws[row * PITCH + q4 * 4 + 2] = f2bf(DN * wv.z);
        Ws[row * PITCH + q4 * 4 + 3] = f2bf(DN * wv.w);
    }
    __syncthreads();

    // ---- FAVOR-q: per-row diag + per-row max ----
    {
        const int row = tid >> 2, seg = tid & 3;
        const us8_t* xp = (const us8_t*)&Qs[row * PITCH + seg * 16];
        us8_t a = xp[0], b2 = xp[1];
        float ss = 0.f, mx = -3.4e38f;
        #pragma unroll
        for (int j = 0; j < 8; ++j) {
            float x0 = bf2f(a[j]), x1 = bf2f(b2[j]);
            ss += x0 * x0 + x1 * x1;
            mx = fmaxf(mx, fmaxf(x0, x1));
        }
        ssp[row][seg] = ss;
        mxp[row][seg] = mx;
    }
    __syncthreads();
    if (tid < 64) {
        diag[tid] = (ssp[tid][0] + ssp[tid][1] + ssp[tid][2] + ssp[tid][3]) * DIAG_SCALE;
        mxr[tid] = DN * fmaxf(fmaxf(mxp[tid][0], mxp[tid][1]),
                              fmaxf(mxp[tid][2], mxp[tid][3]));
    }
    __syncthreads();

    {
        bf8_t xf[2];
        #pragma unroll
        for (int ks = 0; ks < 2; ++ks)
            xf[ks] = *(const bf8_t*)&Qs[(w * 16 + l15) * PITCH + ks * 32 + quad * 8];
        f4_t facc[4] = {};
        #pragma unroll
        for (int dt = 0; dt < 4; ++dt)
            #pragma unroll
            for (int ks = 0; ks < 2; ++ks) {
                bf8_t wfr = *(const bf8_t*)&Ws[(dt * 16 + l15) * PITCH + ks * 32 + quad * 8];
                facc[dt] = __builtin_amdgcn_mfma_f32_16x16x32_bf16(xf[ks], wfr, facc[dt], 0, 0, 0);
            }
        __syncthreads();
        #pragma unroll
        for (int r = 0; r < 4; ++r) {
            int row = w * 16 + quad * 4 + r;
            float d_ = diag[row], m_ = mxr[row];
            #pragma unroll
            for (int dt = 0; dt < 4; ++dt) {
                float e = facc[dt][r] - d_ - m_ + 1e-8f;
                Qs[row * PITCH + dt * 16 + l15] = f2bf(INV_SQRT_M * expf(e));
            }
        }
    }
    __syncthreads();

    // ---- FAVOR-k: reload Ws with DN*Wfk; diag over raw Ks; (b,h) max scalar ----
    const float4* Wk4 = (const float4*)Wfk;
    #pragma unroll
    for (int i = 0; i < 4; ++i) {
        int f4i = tid + i * 256;
        int row = f4i >> 4, q4 = f4i & 15;
        float4 wv = Wk4[f4i];
        Ws[row * PITCH + q4 * 4 + 0] = f2bf(DN * wv.x);
        Ws[row * PITCH + q4 * 4 + 1] = f2bf(DN * wv.y);
        Ws[row * PITCH + q4 * 4 + 2] = f2bf(DN * wv.z);
        Ws[row * PITCH + q4 * 4 + 3] = f2bf(DN * wv.w);
    }
    {
        const int row = tid >> 2, seg = tid & 3;
        const us8_t* xp = (const us8_t*)&Ks[row * PITCH + seg * 16];
        us8_t a = xp[0], b2 = xp[1];
        float ss = 0.f;
        #pragma unroll
        for (int j = 0; j < 8; ++j) {
            float x0 = bf2f(a[j]), x1 = bf2f(b2[j]);
            ss += x0 * x0 + x1 * x1;
        }
        ssp[row][seg] = ss;
    }
    __syncthreads();
    if (tid < 64)
        diag[tid] = (ssp[tid][0] + ssp[tid][1] + ssp[tid][2] + ssp[tid][3]) * DIAG_SCALE;
    unsigned ku = kmOrd[b * NH + h];
    unsigned kbits = (ku & 0x80000000u) ? (ku & 0x7FFFFFFFu) : ~ku;
    const float mxs = DN * __uint_as_float(kbits);
    __syncthreads();

    {
        bf8_t xf[2];
        #pragma unroll
        for (int ks = 0; ks < 2; ++ks)
            xf[ks] = *(const bf8_t*)&Ks[(w * 16 + l15) * PITCH + ks * 32 + quad * 8];
        f4_t facc[4] = {};
        #pragma unroll
        for (int dt = 0; dt < 4; ++dt)
            #pragma unroll
            for (int ks = 0; ks < 2; ++ks) {
                bf8_t wfr = *(const bf8_t*)&Ws[(dt * 16 + l15) * PITCH + ks * 32 + quad * 8];
                facc[dt] = __builtin_amdgcn_mfma_f32_16x16x32_bf16(xf[ks], wfr, facc[dt], 0, 0, 0);
            }
        __syncthreads();          // all raw-Ks reads done before in-place write
        #pragma unroll
        for (int r = 0; r < 4; ++r) {
            int row = w * 16 + quad * 4 + r;
            float d_ = diag[row];
            #pragma unroll
            for (int dt = 0; dt < 4; ++dt) {
                float e = facc[dt][r] - d_ - mxs + 1e-8f;
                Ks[row * PITCH + dt * 16 + l15] = f2bf(INV_SQRT_M * expf(e));
            }
        }
    }
    __syncthreads();

    // ---- QK^T (both favor'd) ----
    bf8_t qf[2];
    #pragma unroll
    for (int ks = 0; ks < 2; ++ks)
        qf[ks] = *(const bf8_t*)&Qs[(w * 16 + l15) * PITCH + ks * 32 + quad * 8];
    f4_t accA[4] = {};
    #pragma unroll
    for (int jt = 0; jt < 4; ++jt)
        #pragma unroll
        for (int ks = 0; ks < 2; ++ks) {
            bf8_t kf = *(const bf8_t*)&Ks[(jt * 16 + l15) * PITCH + ks * 32 + quad * 8];
            accA[jt] = __builtin_amdgcn_mfma_f32_16x16x32_bf16(qf[ks], kf, accA[jt], 0, 0, 0);
        }
    __syncthreads();
    #pragma unroll
    for (int jt = 0; jt < 4; ++jt) {
        int j = jt * 16 + l15;
        #pragma unroll
        for (int r = 0; r < 4; ++r) {
            int i = w * 16 + quad * 4 + r;
            float a = (j <= i) ? accA[jt][r] : 0.f;
            Ks[i * PITCH + j] = f2bf(a);
        }
    }
    __syncthreads();

    bf8_t af[2];
    #pragma unroll
    for (int ks = 0; ks < 2; ++ks)
        af[ks] = *(const bf8_t*)&Ks[(w * 16 + l15) * PITCH + ks * 32 + quad * 8];
    f4_t acc[5] = {};
    #pragma unroll
    for (int dt = 0; dt < 5; ++dt)
        #pragma unroll
        for (int ks = 0; ks < 2; ++ks) {
            bf8_t sf = *(const bf8_t*)&St[(dt * 16 + l15) * PITCH + ks * 32 + quad * 8];
            acc[dt] = __builtin_amdgcn_mfma_f32_16x16x32_bf16(qf[ks], sf, acc[dt], 0, 0, 0);
            bf8_t vf = *(const bf8_t*)&Vt[(dt * 16 + l15) * PITCH + ks * 32 + quad * 8];
            acc[dt] = __builtin_amdgcn_mfma_f32_16x16x32_bf16(af[ks], vf, acc[dt], 0, 0, 0);
        }
    if (l15 == 0) {
        #pragma unroll
        for (int r = 0; r < 4; ++r) dens[w * 16 + quad * 4 + r] = acc[4][r];
    }
    __syncthreads();

    #pragma unroll
    for (int r = 0; r < 4; ++r) {
        int i = w * 16 + quad * 4 + r;
        float inv = 1.0f / dens[i];
        #pragma unroll
        for (int dt = 0; dt < 4; ++dt)
            Obf[gbase + (size_t)i * DM + dt * 16 + l15] = f2bf(acc[dt][r] * inv);
    }
}

// ---------------------------------------------------------------------------
extern "C" void kernel_launch(void* const* d_in, const int* in_sizes, int n_in,
                              void* d_out, int out_size, void* d_ws, size_t ws_size,
                              hipStream_t stream)
{
    const float* queries = (const float*)d_in[0];
    const float* keys    = (const float*)d_in[1];
    const float* values  = (const float*)d_in[2];
    const float* Wq = (const float*)d_in[3];  const float* bq = (const float*)d_in[4];
    const float* Wk = (const float*)d_in[5];  const float* bk = (const float*)d_in[6];
    const float* Wv = (const float*)d_in[7];  const float* bv = (const float*)d_in[8];
    const float* Wo = (const float*)d_in[9];  const float* bo = (const float*)d_in[10];
    const float* Wfq = (const float*)d_in[11];
    const float* Wfk = (const float*)d_in[12];

    char* ws = (char*)d_ws;
    unsigned* kmOrd = (unsigned*)ws;                       // [32] (pad)
    ushort_t* STb = (ushort_t*)(ws + 256);                 // [32,64,65*64] bf16
    ushort_t* qbf = STb + (size_t)32 * NCHUNK * STSZ;      // qkv bf16 GEMM outputs
    ushort_t* kbf = qbf + (size_t)NROW * DM;
    ushort_t* vbf = kbf + (size_t)NROW * DM;
    ushort_t* obf = vbf + (size_t)NROW * DM;               // bf16 attn out
    ushort_t* xcvt = obf + (size_t)NROW * DM;              // 3x bf16 converted inputs
    ushort_t* wT  = xcvt + (size_t)3 * NROW * DM;          // 4 x [1024,1024] bf16
    ushort_t* WoT = wT + (size_t)3 * DM * DM;

    prep_weights<<<dim3(32, 32, 4), 256, 0, stream>>>(Wq, Wk, Wv, Wo, wT, kmOrd);

    const int n8 = NROW * DM / 8;
    cvt_qkv<<<dim3(n8 / 256, 3), 256, 0, stream>>>(queries, keys, values, xcvt);

    gemm_qkv<<<dim3(512, 3), 256, 0, stream>>>(xcvt, wT, bq, bk, bv, qbf, kmOrd);

    chunk_sums_mfma<<<BATCH * NH * NCHUNK, 256, 0, stream>>>(kbf, vbf, Wfk, kmOrd, STb);
    prefix_scan_st<<<32 * 17, 256, 0, stream>>>(STb);
    intra_attn_mfma<<<BATCH * NH * NCHUNK, 256, 0, stream>>>(qbf, kbf, vbf, STb,
                                                             Wfq, Wfk, kmOrd, obf);

    gemm_out<<<512, 256, 0, stream>>>(obf, WoT, bo, (float*)d_out);
}

// Round 9
// 308.124 us; speedup vs baseline: 1.1121x; 1.0085x over previous
//
#include <hip/hip_runtime.h>
#include <math.h>

// Problem constants: B=2, L=4096, d_model=1024, H=16, M=D=64
#define BATCH 2
#define SEQ   4096
#define DM    1024
#define NH    16
#define MD    64
#define NROW  (BATCH*SEQ)     // 8192
#define RQ    (BATCH*SEQ*NH)  // 131072
#define NCHUNK 64
#define CT     64
#define DN    0.35355339059327373f
#define INV_SQRT_M 0.125f
#define PITCH 72              // ushort row pitch for bf16 LDS tiles
#define STSZ  (65*64)         // per-(bh,c) S^T chunk: rows d=0..64 (row 64 = z)
#define DIAG_SCALE (0.125f * 0.0625f)   // DN^2 * 0.5*DN^2

typedef unsigned short ushort_t;
typedef short bf8_t __attribute__((ext_vector_type(8)));
typedef float f4_t  __attribute__((ext_vector_type(4)));
typedef ushort_t us8_t __attribute__((ext_vector_type(8)));

__device__ static inline ushort_t f2bf(float f) {
    union { float f; unsigned u; } v; v.f = f;
    unsigned r = v.u + 0x7FFFu + ((v.u >> 16) & 1u);   // RNE
    return (ushort_t)(r >> 16);
}
__device__ static inline float bf2f(ushort_t u) {
    union { unsigned u; float f; } v; v.u = ((unsigned)u) << 16;
    return v.f;
}

__device__ static inline void async_ld16(const ushort_t* g, ushort_t* l) {
    __builtin_amdgcn_global_load_lds(
        (const __attribute__((address_space(1))) unsigned int*)g,
        (__attribute__((address_space(3))) unsigned int*)l,
        16, 0, 0);
}

__device__ static inline void sbar() {
    __builtin_amdgcn_sched_barrier(0);
    __builtin_amdgcn_s_barrier();
    __builtin_amdgcn_sched_barrier(0);
}
#define VMCNT(n) do { asm volatile("s_waitcnt vmcnt(" #n ")" ::: "memory"); \
                      __builtin_amdgcn_sched_barrier(0); } while (0)

#define ABUF (128*64)   // ushorts: A tile buffer (16 KiB)
#define BBUF (256*64)   // ushorts: B tile buffer (32 KiB)
#define TBUF (128*64)   // ushorts per 128^2 tile buffer (16 KiB)

// ---------------------------------------------------------------------------
// 128x256-tile bf16 GEMM core (best measured for gemm_qkv: 80.3-81.5 us).
// 512 threads = 8 waves (2M x 4N), per-wave output 64x64, BK=64, K=1024.
// LDS: A[2][128][64] (32K) + B[2][256][64] (64K) = 96 KiB.
// T2 swizzle: LDS dest linear (global_load_lds); global SOURCE col pre-XOR'd;
// read slot XOR'd with row&7. SQ_LDS_BANK_CONFLICT = 0 (HW-verified).
// ---------------------------------------------------------------------------
__device__ static inline void gemm128_core(
    const ushort_t* __restrict__ A, const ushort_t* __restrict__ BT,
    ushort_t* As, ushort_t* Bs, int bm, int bn, int tid, f4_t acc[4][4])
{
    const int lane = tid & 63, w = tid >> 6;        // 8 waves
    const int wr = w >> 2, wc = w & 3;              // 2 x 4 wave grid
    const int quad = lane >> 4, l15 = lane & 15;
    const int lrow = lane >> 3;                     // 0..7
    const int kcol = ((lane & 7) ^ lrow) * 8;       // inverse-swizzled src col

    auto stB = [&](int t, int s) {                  // B tile: 4 loads/thread
        #pragma unroll
        for (int c = 0; c < 4; ++c) {
            const int r0 = c * 64 + w * 8;
            async_ld16(BT + (size_t)(bn + r0 + lrow) * DM + t * 64 + kcol,
                       &Bs[s * BBUF + r0 * 64]);
        }
    };
    auto stA1 = [&](int t, int s) {                 // A rows {[0,32),[64,96)}
        const int r0 = (w < 4) ? w * 8 : 32 + w * 8;
        async_ld16(A + (size_t)(bm + r0 + lrow) * DM + t * 64 + kcol,
                   &As[s * ABUF + r0 * 64]);
    };
    auto stA2 = [&](int t, int s) {                 // A rows {[32,64),[96,128)}
        const int r0 = (w < 4) ? 32 + w * 8 : 64 + w * 8;
        async_ld16(A + (size_t)(bm + r0 + lrow) * DM + t * 64 + kcol,
                   &As[s * ABUF + r0 * 64]);
    };

    auto loadB = [&](int s, bf8_t bf[2][4]) {
        #pragma unroll
        for (int ks = 0; ks < 2; ++ks) {
            const int slot8 = (((ks << 2) | quad) ^ (l15 & 7)) * 8;
            #pragma unroll
            for (int j = 0; j < 4; ++j) {
                const int row = wc * 64 + j * 16 + l15;
                bf[ks][j] = *(const bf8_t*)&Bs[s * BBUF + row * 64 + slot8];
            }
        }
    };
    auto loadA = [&](int s, int ih, bf8_t af[2][2]) {
        #pragma unroll
        for (int ks = 0; ks < 2; ++ks) {
            const int slot8 = (((ks << 2) | quad) ^ (l15 & 7)) * 8;
            #pragma unroll
            for (int i = 0; i < 2; ++i) {
                const int row = wr * 64 + (ih * 2 + i) * 16 + l15;
                af[ks][i] = *(const bf8_t*)&As[s * ABUF + row * 64 + slot8];
            }
        }
    };
    auto mfma16 = [&](int ih, bf8_t af[2][2], bf8_t bf[2][4]) {
        __builtin_amdgcn_s_setprio(1);
        #pragma unroll
        for (int ks = 0; ks < 2; ++ks)
            #pragma unroll
            for (int i = 0; i < 2; ++i)
                #pragma unroll
                for (int j = 0; j < 4; ++j)
                    acc[ih * 2 + i][j] = __builtin_amdgcn_mfma_f32_16x16x32_bf16(
                        af[ks][i], bf[ks][j], acc[ih * 2 + i][j], 0, 0, 0);
        __builtin_amdgcn_s_setprio(0);
    };

    stB(0, 0); stA1(0, 0);
    stA2(0, 0);
    stB(1, 1); stA1(1, 1);
    VMCNT(6);
    sbar();

    bf8_t bf[2][4], af[2][2];
    #pragma unroll 1
    for (int v = 0; v < 7; ++v) {
        const int u0 = 2 * v;
        loadB(0, bf); loadA(0, 0, af);
        stA2(u0 + 1, 1);
        VMCNT(6); sbar();
        mfma16(0, af, bf);
        sbar();
        loadA(0, 1, af);
        stB(u0 + 2, 0); stA1(u0 + 2, 0);
        VMCNT(6); sbar();
        mfma16(1, af, bf);
        sbar();
        loadB(1, bf); loadA(1, 0, af);
        stA2(u0 + 2, 0);
        VMCNT(6); sbar();
        mfma16(0, af, bf);
        sbar();
        loadA(1, 1, af);
        stB(u0 + 3, 1); stA1(u0 + 3, 1);
        VMCNT(6); sbar();
        mfma16(1, af, bf);
        sbar();
    }
    loadB(0, bf); loadA(0, 0, af);
    stA2(15, 1);
    VMCNT(6); sbar();
    mfma16(0, af, bf);
    sbar();
    loadA(0, 1, af);
    VMCNT(1); sbar();
    mfma16(1, af, bf);
    sbar();
    loadB(1, bf); loadA(1, 0, af);
    VMCNT(0); sbar();
    mfma16(0, af, bf);
    sbar();
    loadA(1, 1, af);
    mfma16(1, af, bf);
}

// XCD-aware bijective remap of 256 blocks (64 bm x 4 bn panels of 128x256).
__device__ static inline void swz256(int bx, int* bm, int* bn) {
    const int xcd = bx & 7, s = bx >> 3;
    *bm = (xcd * 8 + (s >> 2)) << 7;
    *bn = (s & 3) << 8;
}

// ---------------------------------------------------------------------------
// 128x128-tile bf16 GEMM core (best measured for gemm_out: 512-block grid,
// 2 blocks/CU, exact 1-round fill). 256 threads = 4 waves (2M x 2N).
// ---------------------------------------------------------------------------
__device__ static inline void gemm_tile_core(
    const ushort_t* __restrict__ A, const ushort_t* __restrict__ BT,
    ushort_t* As, ushort_t* Bs, int bm, int bn, int tid, f4_t acc[4][4])
{
    const int lane = tid & 63, w = tid >> 6;        // 4 waves
    const int wr = w >> 1, wc = w & 1;              // 2 x 2 wave grid
    const int quad = lane >> 4, l15 = lane & 15;
    const int lrow = lane >> 3;                     // 0..7
    const int kcol = ((lane & 7) ^ lrow) * 8;       // inverse-swizzled src col

    auto stA = [&](int t, int s) {                  // 4 loads/thread
        #pragma unroll
        for (int c = 0; c < 4; ++c) {
            const int r0 = c * 32 + w * 8;
            async_ld16(A + (size_t)(bm + r0 + lrow) * DM + t * 64 + kcol,
                       &As[s * TBUF + r0 * 64]);
        }
    };
    auto stB = [&](int t, int s) {
        #pragma unroll
        for (int c = 0; c < 4; ++c) {
            const int r0 = c * 32 + w * 8;
            async_ld16(BT + (size_t)(bn + r0 + lrow) * DM + t * 64 + kcol,
                       &Bs[s * TBUF + r0 * 64]);
        }
    };

    bf8_t af[4], bf[4];
    auto rdFrags = [&](int s, int ks) {
        const int slot8 = (((ks << 2) | quad) ^ (l15 & 7)) * 8;
        #pragma unroll
        for (int i = 0; i < 4; ++i)
            af[i] = *(const bf8_t*)&As[s * TBUF + (wr * 64 + i * 16 + l15) * 64 + slot8];
        #pragma unroll
        for (int j = 0; j < 4; ++j)
            bf[j] = *(const bf8_t*)&Bs[s * TBUF + (wc * 64 + j * 16 + l15) * 64 + slot8];
    };
    auto mm = [&]() {
        __builtin_amdgcn_s_setprio(1);
        #pragma unroll
        for (int i = 0; i < 4; ++i)
            #pragma unroll
            for (int j = 0; j < 4; ++j)
                acc[i][j] = __builtin_amdgcn_mfma_f32_16x16x32_bf16(
                    af[i], bf[j], acc[i][j], 0, 0, 0);
        __builtin_amdgcn_s_setprio(0);
    };

    stA(0, 0); stB(0, 0);

    #pragma unroll 1
    for (int t = 0; t < 15; ++t) {
        const int s = t & 1;
        stA(t + 1, s ^ 1); stB(t + 1, s ^ 1);   // 8 newest
        VMCNT(8);                               // publishes A,B(t) -> buf s
        sbar();
        rdFrags(s, 0);
        mm();
        rdFrags(s, 1);
        mm();
        sbar();                                 // all reads of buf s done
    }
    VMCNT(0);
    sbar();
    rdFrags(1, 0);
    mm();
    rdFrags(1, 1);
    mm();
}

// XCD-aware bijective remap of 512 blocks (64 bm x 8 bn panels of 128x128).
__device__ static inline void swz512(int bx, int* bm, int* bn) {
    const int xcd = bx & 7, s = bx >> 3;        // s: 0..63
    *bm = (xcd * 8 + (s >> 3)) << 7;
    *bn = (s & 7) << 7;
}

// ---------------------------------------------------------------------------
// MERGED prep + cvt (one dispatch instead of two):
//   bx <  12288: fp32->bf16 convert of q/k/v (y = bx/4096)
//   bx >= 12288: weight transpose_cvt (4 x 1024x1024) + kmOrd zero
// Branch is block-uniform -> no divergence cost; prep blocks backfill CUs
// alongside the HBM-bound cvt blocks.
// ---------------------------------------------------------------------------
__global__ __launch_bounds__(256) void prep_cvt(
    const float* __restrict__ Q, const float* __restrict__ K,
    const float* __restrict__ V, ushort_t* __restrict__ Y,
    const float* __restrict__ W0, const float* __restrict__ W1,
    const float* __restrict__ W2, const float* __restrict__ W3,
    ushort_t* __restrict__ WT, unsigned* __restrict__ kmOrd)
{
    const int bx = blockIdx.x;
    if (bx < 12288) {
        const int y = bx >> 12;                 // 0..2
        const float* X = y == 0 ? Q : (y == 1 ? K : V);
        ushort_t* dst = Y + (size_t)y * NROW * DM;
        int i = (bx & 4095) * 256 + threadIdx.x;
        const float4* X4 = (const float4*)X;
        float4 a = X4[i * 2], b = X4[i * 2 + 1];
        us8_t o;
        o[0]=f2bf(a.x); o[1]=f2bf(a.y); o[2]=f2bf(a.z); o[3]=f2bf(a.w);
        o[4]=f2bf(b.x); o[5]=f2bf(b.y); o[6]=f2bf(b.z); o[7]=f2bf(b.w);
        *(us8_t*)&dst[i * 8] = o;
        return;
    }
    const int pbx = bx - 12288;                 // 0..4095
    if (pbx == 0 && threadIdx.x < 32) kmOrd[threadIdx.x] = 0u;
    const int z = pbx >> 10;                    // 0..3
    const int rem = pbx & 1023;
    const int kx = rem & 31, ny = rem >> 5;
    const float* W = z == 0 ? W0 : (z == 1 ? W1 : (z == 2 ? W2 : W3));
    ushort_t* dst = WT + (size_t)z * DM * DM;
    __shared__ float t[32][33];
    const int k0 = kx * 32, n0 = ny * 32;
    const int tx = threadIdx.x & 31, ty = threadIdx.x >> 5;
    #pragma unroll
    for (int r = 0; r < 32; r += 8)
        t[ty + r][tx] = W[(size_t)(k0 + ty + r) * 1024 + n0 + tx];
    __syncthreads();
    #pragma unroll
    for (int r = 0; r < 32; r += 8)
        dst[(size_t)(n0 + ty + r) * 1024 + k0 + tx] = f2bf(t[tx][ty + r]);
}

// ---------------------------------------------------------------------------
// merged QKV GEMM (128x256 tiles, round-7 best-measured config).
// z==1 (keys) folds per-(b,h) output max into kmOrd via ordered-uint atomicMax.
// ---------------------------------------------------------------------------
__global__ __launch_bounds__(512, 2) void gemm_qkv(
    const ushort_t* __restrict__ Xc, const ushort_t* __restrict__ WT,
    const float* __restrict__ bq, const float* __restrict__ bk,
    const float* __restrict__ bv, ushort_t* __restrict__ Obase,
    unsigned* __restrict__ kmOrd)
{
    __shared__ ushort_t As[2 * ABUF];
    __shared__ ushort_t Bs[2 * BBUF];
    const int z = blockIdx.y;
    const ushort_t* A  = Xc + (size_t)z * NROW * DM;
    const ushort_t* BT = WT + (size_t)z * DM * DM;
    const float* bias = z == 0 ? bq : (z == 1 ? bk : bv);
    ushort_t* Cbf = Obase + (size_t)z * NROW * DM;

    const int tid = threadIdx.x;
    int bm, bn;
    swz256(blockIdx.x, &bm, &bn);
    const int lane = tid & 63, w = tid >> 6;
    const int wr = w >> 2, wc = w & 3;
    const int quad = lane >> 4, l15 = lane & 15;

    f4_t acc[4][4] = {};
    gemm128_core(A, BT, As, Bs, bm, bn, tid, acc);

    float mx = -3.4e38f;
    #pragma unroll
    for (int j = 0; j < 4; ++j) {
        const int col = bn + wc * 64 + j * 16 + l15;
        const float bb = bias[col];
        #pragma unroll
        for (int i = 0; i < 4; ++i) {
            const int row0 = bm + wr * 64 + i * 16 + quad * 4;
            #pragma unroll
            for (int r = 0; r < 4; ++r) {
                float v = acc[i][j][r] + bb;
                mx = fmaxf(mx, v);
                Cbf[(size_t)(row0 + r) * DM + col] = f2bf(v);
            }
        }
    }
    if (z == 1) {
        // wave covers one (b,h): rows bm..bm+127 (one b), cols bn+wc*64..+64.
        #pragma unroll
        for (int off = 32; off; off >>= 1) mx = fmaxf(mx, __shfl_xor(mx, off));
        if (lane == 0) {
            const int b = bm >> 12;
            const int h = (bn + wc * 64) >> 6;
            unsigned ub = __float_as_uint(mx);
            unsigned enc = (ub & 0x80000000u) ? ~ub : (ub | 0x80000000u);
            atomicMax(&kmOrd[b * NH + h], enc);
        }
    }
}

// ---------------------------------------------------------------------------
// final GEMM (128x128 tiles, 512 blocks, 2 blocks/CU): obf @ WoT + bo -> fp32
// ---------------------------------------------------------------------------
__global__ __launch_bounds__(256, 2) void gemm_out(
    const ushort_t* __restrict__ A, const ushort_t* __restrict__ BT,
    const float* __restrict__ bias, float* __restrict__ C)
{
    __shared__ ushort_t As[2 * TBUF];
    __shared__ ushort_t Bs[2 * TBUF];
    const int tid = threadIdx.x;
    int bm, bn;
    swz512(blockIdx.x, &bm, &bn);
    const int lane = tid & 63, w = tid >> 6;
    const int wr = w >> 1, wc = w & 1;
    const int quad = lane >> 4, l15 = lane & 15;

    f4_t acc[4][4] = {};
    gemm_tile_core(A, BT, As, Bs, bm, bn, tid, acc);

    #pragma unroll
    for (int j = 0; j < 4; ++j) {
        const int col = bn + wc * 64 + j * 16 + l15;
        const float bb = bias[col];
        #pragma unroll
        for (int i = 0; i < 4; ++i) {
            const int row0 = bm + wr * 64 + i * 16 + quad * 4;
            #pragma unroll
            for (int r = 0; r < 4; ++r)
                C[(size_t)(row0 + r) * DM + col] = acc[i][j][r] + bb;
        }
    }
}

// ---------------------------------------------------------------------------
// chunk_sums (MFMA) with INLINE FAVOR-K.
// ---------------------------------------------------------------------------
__global__ __launch_bounds__(256) void chunk_sums_mfma(
    const ushort_t* __restrict__ Kbf, const ushort_t* __restrict__ Vbf,
    const float* __restrict__ Wfk, const unsigned* __restrict__ kmOrd,
    ushort_t* __restrict__ ST)
{
    const int bx = blockIdx.x;
    const int c = bx & 63, h = (bx >> 6) & 15, b = bx >> 10;
    __shared__ ushort_t Ks[64 * PITCH];   // raw K rows [t][m]
    __shared__ ushort_t Kt[64 * PITCH];   // favor'd K transposed [m][t]
    __shared__ ushort_t Vt[80 * PITCH];
    __shared__ ushort_t Ws[64 * PITCH];
    __shared__ float ssp[64][4];
    __shared__ float diag[64];
    const int tid = threadIdx.x;
    const int lane = tid & 63, w = tid >> 6;
    const int quad = lane >> 4, l15 = lane & 15;

    const size_t gbase = ((size_t)(b * SEQ + c * CT)) * DM + h * MD;

    #pragma unroll
    for (int r = 0; r < 2; ++r) {
        int idx = tid + r * 256;
        int row = idx >> 3, ch = idx & 7;
        *(us8_t*)&Ks[row * PITCH + ch * 8] =
            *(const us8_t*)&Kbf[gbase + (size_t)row * DM + ch * 8];
    }
    #pragma unroll
    for (int r = 0; r < 2; ++r) {
        int ch = w + r * 4;
        int t = lane;
        us8_t vv = *(const us8_t*)&Vbf[gbase + (size_t)t * DM + ch * 8];
        #pragma unroll
        for (int j = 0; j < 8; ++j) Vt[(ch * 8 + j) * PITCH + t] = vv[j];
    }
    if (tid < 64) Vt[64 * PITCH + tid] = (ushort_t)0x3F80;
    const float4* Wf4 = (const float4*)Wfk;
    #pragma unroll
    for (int i = 0; i < 4; ++i) {
        int f4i = tid + i * 256;
        int row = f4i >> 4, q4 = f4i & 15;
        float4 wv = Wf4[f4i];
        Ws[row * PITCH + q4 * 4 + 0] = f2bf(DN * wv.x);
        Ws[row * PITCH + q4 * 4 + 1] = f2bf(DN * wv.y);
        Ws[row * PITCH + q4 * 4 + 2] = f2bf(DN * wv.z);
        Ws[row * PITCH + q4 * 4 + 3] = f2bf(DN * wv.w);
    }
    __syncthreads();

    {
        const int row = tid >> 2, seg = tid & 3;
        const us8_t* xp = (const us8_t*)&Ks[row * PITCH + seg * 16];
        us8_t a = xp[0], b2 = xp[1];
        float ss = 0.f;
        #pragma unroll
        for (int j = 0; j < 8; ++j) {
            float x0 = bf2f(a[j]), x1 = bf2f(b2[j]);
            ss += x0 * x0 + x1 * x1;
        }
        ssp[row][seg] = ss;
    }
    __syncthreads();
    if (tid < 64)
        diag[tid] = (ssp[tid][0] + ssp[tid][1] + ssp[tid][2] + ssp[tid][3]) * DIAG_SCALE;
    unsigned u = kmOrd[b * NH + h];
    unsigned bits = (u & 0x80000000u) ? (u & 0x7FFFFFFFu) : ~u;
    const float mxs = DN * __uint_as_float(bits);
    __syncthreads();

    {
        bf8_t xf[2];
        #pragma unroll
        for (int ks = 0; ks < 2; ++ks)
            xf[ks] = *(const bf8_t*)&Ks[(w * 16 + l15) * PITCH + ks * 32 + quad * 8];
        f4_t facc[4] = {};
        #pragma unroll
        for (int dt = 0; dt < 4; ++dt)
            #pragma unroll
            for (int ks = 0; ks < 2; ++ks) {
                bf8_t wfr = *(const bf8_t*)&Ws[(dt * 16 + l15) * PITCH + ks * 32 + quad * 8];
                facc[dt] = __builtin_amdgcn_mfma_f32_16x16x32_bf16(xf[ks], wfr, facc[dt], 0, 0, 0);
            }
        #pragma unroll
        for (int r = 0; r < 4; ++r) {
            int t = w * 16 + quad * 4 + r;
            float d_ = diag[t];
            #pragma unroll
            for (int dt = 0; dt < 4; ++dt) {
                float e = facc[dt][r] - d_ - mxs + 1e-8f;
                Kt[(dt * 16 + l15) * PITCH + t] = f2bf(INV_SQRT_M * expf(e));
            }
        }
    }
    __syncthreads();

    ushort_t* Sg = ST + (size_t)((b * NH + h) * NCHUNK + c) * STSZ;

    bf8_t vf[2];
    #pragma unroll
    for (int ks = 0; ks < 2; ++ks)
        vf[ks] = *(const bf8_t*)&Vt[(w * 16 + l15) * PITCH + ks * 32 + quad * 8];
    f4_t acc[4] = {};
    #pragma unroll
    for (int mt = 0; mt < 4; ++mt)
        #pragma unroll
        for (int ks = 0; ks < 2; ++ks) {
            bf8_t kf = *(const bf8_t*)&Kt[(mt * 16 + l15) * PITCH + ks * 32 + quad * 8];
            acc[mt] = __builtin_amdgcn_mfma_f32_16x16x32_bf16(vf[ks], kf, acc[mt], 0, 0, 0);
        }
    #pragma unroll
    for (int mt = 0; mt < 4; ++mt)
        #pragma unroll
        for (int r = 0; r < 4; ++r)
            Sg[(w * 16 + quad * 4 + r) * 64 + mt * 16 + l15] = f2bf(acc[mt][r]);

    if (w == 0) {
        bf8_t vf4[2];
        #pragma unroll
        for (int ks = 0; ks < 2; ++ks)
            vf4[ks] = *(const bf8_t*)&Vt[(64 + l15) * PITCH + ks * 32 + quad * 8];
        f4_t accz[4] = {};
        #pragma unroll
        for (int mt = 0; mt < 4; ++mt)
            #pragma unroll
            for (int ks = 0; ks < 2; ++ks) {
                bf8_t kf = *(const bf8_t*)&Kt[(mt * 16 + l15) * PITCH + ks * 32 + quad * 8];
                accz[mt] = __builtin_amdgcn_mfma_f32_16x16x32_bf16(vf4[ks], kf, accz[mt], 0, 0, 0);
            }
        if (quad == 0) {
            #pragma unroll
            for (int mt = 0; mt < 4; ++mt)
                Sg[64 * 64 + mt * 16 + l15] = f2bf(accz[mt][0]);
        }
    }
}

// ---------------------------------------------------------------------------
// Exclusive prefix over chunks on bf16 ST; register-pipelined.
// ---------------------------------------------------------------------------
__global__ __launch_bounds__(256) void prefix_scan_st(ushort_t* __restrict__ ST)
{
    const int sb = blockIdx.x / 17;
    const int e = (blockIdx.x % 17) * 256 + threadIdx.x;
    if (e >= STSZ) return;
    ushort_t* p = ST + (size_t)sb * NCHUNK * STSZ + e;
    ushort_t v[NCHUNK];
    #pragma unroll
    for (int c = 0; c < NCHUNK; ++c) v[c] = p[(size_t)c * STSZ];
    float run = 0.f;
    #pragma unroll
    for (int c = 0; c < NCHUNK; ++c) {
        float cur = bf2f(v[c]);
        p[(size_t)c * STSZ] = f2bf(run);
        run += cur;
    }
}

// ---------------------------------------------------------------------------
// intra-chunk causal attention (MFMA) with inline FAVOR-q AND FAVOR-k.
// ---------------------------------------------------------------------------
__global__ __launch_bounds__(256) void intra_attn_mfma(
    const ushort_t* __restrict__ Qraw, const ushort_t* __restrict__ Kbf,
    const ushort_t* __restrict__ Vbf, const ushort_t* __restrict__ ST,
    const float* __restrict__ Wfq, const float* __restrict__ Wfk,
    const unsigned* __restrict__ kmOrd, ushort_t* __restrict__ Obf)
{
    const int bx = blockIdx.x;
    const int c = bx & 63, h = (bx >> 6) & 15, b = bx >> 10;
    __shared__ ushort_t Qs[64 * PITCH];
    __shared__ ushort_t Ks[64 * PITCH];
    __shared__ ushort_t Vt[80 * PITCH];
    __shared__ ushort_t St[80 * PITCH];
    __shared__ ushort_t Ws[64 * PITCH];
    __shared__ float ssp[64][4];
    __shared__ float mxp[64][4];
    __shared__ float diag[64], mxr[64], dens[64];
    const int tid = threadIdx.x;
    const int lane = tid & 63, w = tid >> 6;
    const int quad = lane >> 4, l15 = lane & 15;

    const size_t gbase = ((size_t)(b * SEQ + c * CT)) * DM + h * MD;

    #pragma unroll
    for (int r = 0; r < 2; ++r) {
        int idx = tid + r * 256;
        int row = idx >> 3, ch = idx & 7;
        us8_t qv = *(const us8_t*)&Qraw[gbase + (size_t)row * DM + ch * 8];
        us8_t kv = *(const us8_t*)&Kbf[gbase + (size_t)row * DM + ch * 8];
        *(us8_t*)&Qs[row * PITCH + ch * 8] = qv;
        *(us8_t*)&Ks[row * PITCH + ch * 8] = kv;
    }
    #pragma unroll
    for (int r = 0; r < 2; ++r) {
        int ch = w + r * 4;
        int t = lane;
        us8_t vv = *(const us8_t*)&Vbf[gbase + (size_t)t * DM + ch * 8];
        #pragma unroll
        for (int j = 0; j < 8; ++j) Vt[(ch * 8 + j) * PITCH + t] = vv[j];
    }
    #pragma unroll
    for (int r = 0; r < 4; ++r) {
        int idx = tid + r * 256;
        int row = 64 + (idx >> 6), t = idx & 63;
        Vt[row * PITCH + t] = (row == 64) ? (ushort_t)0x3F80 : (ushort_t)0;
    }
    const us8_t* Sg8 = (const us8_t*)(ST + (size_t)((b * NH + h) * NCHUNK + c) * STSZ);
    #pragma unroll
    for (int r = 0; r < 3; ++r) {
        int idx = tid + r * 256;
        if (idx < 520) {
            int d = idx >> 3, mo = (idx & 7) * 8;
            *(us8_t*)&St[d * PITCH + mo] = Sg8[idx];
        }
        int idx2 = idx - 520;
        if (idx2 >= 0 && idx2 < 120) {
            int row = 65 + (idx2 >> 3), mo = (idx2 & 7) * 8;
            us8_t z = {};
            *(us8_t*)&St[row * PITCH + mo] = z;
        }
    }
    const float4* Wq4 = (const float4*)Wfq;
    #pragma unroll
    for (int i = 0; i < 4; ++i) {
        int f4i = tid + i * 256;
        int row = f4i >> 4, q4 = f4i & 15;
        float4 wv = Wq4[f4i];
        Ws[row * PITCH + q4 * 4 + 0] = f2bf(DN * wv.x);
        Ws[row * PITCH + q4 * 4 + 1] = f2bf(DN * wv.y);
        Ws[row * PITCH + q4 * 4 + 2] = f2bf(DN * wv.z);
        Ws[row * PITCH + q4 * 4 + 3] = f2bf(DN * wv.w);
    }
    __syncthreads();

    // ---- FAVOR-q: per-row diag + per-row max ----
    {
        const int row = tid >> 2, seg = tid & 3;
        const us8_t* xp = (const us8_t*)&Qs[row * PITCH + seg * 16];
        us8_t a = xp[0], b2 = xp[1];
        float ss = 0.f, mx = -3.4e38f;
        #pragma unroll
        for (int j = 0; j < 8; ++j) {
            float x0 = bf2f(a[j]), x1 = bf2f(b2[j]);
            ss += x0 * x0 + x1 * x1;
            mx = fmaxf(mx, fmaxf(x0, x1));
        }
        ssp[row][seg] = ss;
        mxp[row][seg] = mx;
    }
    __syncthreads();
    if (tid < 64) {
        diag[tid] = (ssp[tid][0] + ssp[tid][1] + ssp[tid][2] + ssp[tid][3]) * DIAG_SCALE;
        mxr[tid] = DN * fmaxf(fmaxf(mxp[tid][0], mxp[tid][1]),
                              fmaxf(mxp[tid][2], mxp[tid][3]));
    }
    __syncthreads();

    {
        bf8_t xf[2];
        #pragma unroll
        for (int ks = 0; ks < 2; ++ks)
            xf[ks] = *(const bf8_t*)&Qs[(w * 16 + l15) * PITCH + ks * 32 + quad * 8];
        f4_t facc[4] = {};
        #pragma unroll
        for (int dt = 0; dt < 4; ++dt)
            #pragma unroll
            for (int ks = 0; ks < 2; ++ks) {
                bf8_t wfr = *(const bf8_t*)&Ws[(dt * 16 + l15) * PITCH + ks * 32 + quad * 8];
                facc[dt] = __builtin_amdgcn_mfma_f32_16x16x32_bf16(xf[ks], wfr, facc[dt], 0, 0, 0);
            }
        __syncthreads();
        #pragma unroll
        for (int r = 0; r < 4; ++r) {
            int row = w * 16 + quad * 4 + r;
            float d_ = diag[row], m_ = mxr[row];
            #pragma unroll
            for (int dt = 0; dt < 4; ++dt) {
                float e = facc[dt][r] - d_ - m_ + 1e-8f;
                Qs[row * PITCH + dt * 16 + l15] = f2bf(INV_SQRT_M * expf(e));
            }
        }
    }
    __syncthreads();

    // ---- FAVOR-k: reload Ws with DN*Wfk; diag over raw Ks; (b,h) max scalar ----
    const float4* Wk4 = (const float4*)Wfk;
    #pragma unroll
    for (int i = 0; i < 4; ++i) {
        int f4i = tid + i * 256;
        int row = f4i >> 4, q4 = f4i & 15;
        float4 wv = Wk4[f4i];
        Ws[row * PITCH + q4 * 4 + 0] = f2bf(DN * wv.x);
        Ws[row * PITCH + q4 * 4 + 1] = f2bf(DN * wv.y);
        Ws[row * PITCH + q4 * 4 + 2] = f2bf(DN * wv.z);
        Ws[row * PITCH + q4 * 4 + 3] = f2bf(DN * wv.w);
    }
    {
        const int row = tid >> 2, seg = tid & 3;
        const us8_t* xp = (const us8_t*)&Ks[row * PITCH + seg * 16];
        us8_t a = xp[0], b2 = xp[1];
        float ss = 0.f;
        #pragma unroll
        for (int j = 0; j < 8; ++j) {
            float x0 = bf2f(a[j]), x1 = bf2f(b2[j]);
            ss += x0 * x0 + x1 * x1;
        }
        ssp[row][seg] = ss;
    }
    __syncthreads();
    if (tid < 64)
        diag[tid] = (ssp[tid][0] + ssp[tid][1] + ssp[tid][2] + ssp[tid][3]) * DIAG_SCALE;
    unsigned ku = kmOrd[b * NH + h];
    unsigned kbits = (ku & 0x80000000u) ? (ku & 0x7FFFFFFFu) : ~ku;
    const float mxs = DN * __uint_as_float(kbits);
    __syncthreads();

    {
        bf8_t xf[2];
        #pragma unroll
        for (int ks = 0; ks < 2; ++ks)
            xf[ks] = *(const bf8_t*)&Ks[(w * 16 + l15) * PITCH + ks * 32 + quad * 8];
        f4_t facc[4] = {};
        #pragma unroll
        for (int dt = 0; dt < 4; ++dt)
            #pragma unroll
            for (int ks = 0; ks < 2; ++ks) {
                bf8_t wfr = *(const bf8_t*)&Ws[(dt * 16 + l15) * PITCH + ks * 32 + quad * 8];
                facc[dt] = __builtin_amdgcn_mfma_f32_16x16x32_bf16(xf[ks], wfr, facc[dt], 0, 0, 0);
            }
        __syncthreads();          // all raw-Ks reads done before in-place write
        #pragma unroll
        for (int r = 0; r < 4; ++r) {
            int row = w * 16 + quad * 4 + r;
            float d_ = diag[row];
            #pragma unroll
            for (int dt = 0; dt < 4; ++dt) {
                float e = facc[dt][r] - d_ - mxs + 1e-8f;
                Ks[row * PITCH + dt * 16 + l15] = f2bf(INV_SQRT_M * expf(e));
            }
        }
    }
    __syncthreads();

    // ---- QK^T (both favor'd) ----
    bf8_t qf[2];
    #pragma unroll
    for (int ks = 0; ks < 2; ++ks)
        qf[ks] = *(const bf8_t*)&Qs[(w * 16 + l15) * PITCH + ks * 32 + quad * 8];
    f4_t accA[4] = {};
    #pragma unroll
    for (int jt = 0; jt < 4; ++jt)
        #pragma unroll
        for (int ks = 0; ks < 2; ++ks) {
            bf8_t kf = *(const bf8_t*)&Ks[(jt * 16 + l15) * PITCH + ks * 32 + quad * 8];
            accA[jt] = __builtin_amdgcn_mfma_f32_16x16x32_bf16(qf[ks], kf, accA[jt], 0, 0, 0);
        }
    __syncthreads();
    #pragma unroll
    for (int jt = 0; jt < 4; ++jt) {
        int j = jt * 16 + l15;
        #pragma unroll
        for (int r = 0; r < 4; ++r) {
            int i = w * 16 + quad * 4 + r;
            float a = (j <= i) ? accA[jt][r] : 0.f;
            Ks[i * PITCH + j] = f2bf(a);
        }
    }
    __syncthreads();

    bf8_t af[2];
    #pragma unroll
    for (int ks = 0; ks < 2; ++ks)
        af[ks] = *(const bf8_t*)&Ks[(w * 16 + l15) * PITCH + ks * 32 + quad * 8];
    f4_t acc[5] = {};
    #pragma unroll
    for (int dt = 0; dt < 5; ++dt)
        #pragma unroll
        for (int ks = 0; ks < 2; ++ks) {
            bf8_t sf = *(const bf8_t*)&St[(dt * 16 + l15) * PITCH + ks * 32 + quad * 8];
            acc[dt] = __builtin_amdgcn_mfma_f32_16x16x32_bf16(qf[ks], sf, acc[dt], 0, 0, 0);
            bf8_t vf = *(const bf8_t*)&Vt[(dt * 16 + l15) * PITCH + ks * 32 + quad * 8];
            acc[dt] = __builtin_amdgcn_mfma_f32_16x16x32_bf16(af[ks], vf, acc[dt], 0, 0, 0);
        }
    if (l15 == 0) {
        #pragma unroll
        for (int r = 0; r < 4; ++r) dens[w * 16 + quad * 4 + r] = acc[4][r];
    }
    __syncthreads();

    #pragma unroll
    for (int r = 0; r < 4; ++r) {
        int i = w * 16 + quad * 4 + r;
        float inv = 1.0f / dens[i];
        #pragma unroll
        for (int dt = 0; dt < 4; ++dt)
            Obf[gbase + (size_t)i * DM + dt * 16 + l15] = f2bf(acc[dt][r] * inv);
    }
}

// ---------------------------------------------------------------------------
extern "C" void kernel_launch(void* const* d_in, const int* in_sizes, int n_in,
                              void* d_out, int out_size, void* d_ws, size_t ws_size,
                              hipStream_t stream)
{
    const float* queries = (const float*)d_in[0];
    const float* keys    = (const float*)d_in[1];
    const float* values  = (const float*)d_in[2];
    const float* Wq = (const float*)d_in[3];  const float* bq = (const float*)d_in[4];
    const float* Wk = (const float*)d_in[5];  const float* bk = (const float*)d_in[6];
    const float* Wv = (const float*)d_in[7];  const float* bv = (const float*)d_in[8];
    const float* Wo = (const float*)d_in[9];  const float* bo = (const float*)d_in[10];
    const float* Wfq = (const float*)d_in[11];
    const float* Wfk = (const float*)d_in[12];

    char* ws = (char*)d_ws;
    unsigned* kmOrd = (unsigned*)ws;                       // [32] (pad)
    ushort_t* STb = (ushort_t*)(ws + 256);                 // [32,64,65*64] bf16
    ushort_t* qbf = STb + (size_t)32 * NCHUNK * STSZ;      // qkv bf16 GEMM outputs
    ushort_t* kbf = qbf + (size_t)NROW * DM;
    ushort_t* vbf = kbf + (size_t)NROW * DM;
    ushort_t* obf = vbf + (size_t)NROW * DM;               // bf16 attn out
    ushort_t* xcvt = obf + (size_t)NROW * DM;              // 3x bf16 converted inputs
    ushort_t* wT  = xcvt + (size_t)3 * NROW * DM;          // 4 x [1024,1024] bf16
    ushort_t* WoT = wT + (size_t)3 * DM * DM;

    prep_cvt<<<16384, 256, 0, stream>>>(queries, keys, values, xcvt,
                                        Wq, Wk, Wv, Wo, wT, kmOrd);

    gemm_qkv<<<dim3(256, 3), 512, 0, stream>>>(xcvt, wT, bq, bk, bv, qbf, kmOrd);

    chunk_sums_mfma<<<BATCH * NH * NCHUNK, 256, 0, stream>>>(kbf, vbf, Wfk, kmOrd, STb);
    prefix_scan_st<<<32 * 17, 256, 0, stream>>>(STb);
    intra_attn_mfma<<<BATCH * NH * NCHUNK, 256, 0, stream>>>(qbf, kbf, vbf, STb,
                                                             Wfq, Wfk, kmOrd, obf);

    gemm_out<<<512, 256, 0, stream>>>(obf, WoT, bo, (float*)d_out);
}